// Round 2
// baseline (9465.734 us; speedup 1.0000x reference)
//
#include <hip/hip_runtime.h>
#include <hip/hip_bf16.h>

#define B_   32
#define L_   796
#define D_   512
#define H_   8
#define HD_  64
#define FF_  2048
#define CS_  16
#define STR_ 13
#define NC_  61
#define NQT_ 13   // ceil(796/64)
#define MC_  (NC_ * CS_)   // 976 clip rows per batch

// ---------------------------------------------------------------------------
// build clips: gather windows + channel shuffle
// clips[b,n,c,d]:
//   d < 128 : x[b, n*13 + c, d]
//   d >= 128: j=d-128; x[b, n*13 + (j%16), 128 + (j/16)*16 + c]
// ---------------------------------------------------------------------------
__global__ __launch_bounds__(256) void k_build_clips(const float* __restrict__ x,
                                                     float* __restrict__ clips)
{
    long long idx = (long long)blockIdx.x * 256 + threadIdx.x;   // B*NC*CS*D
    int d = idx & 511;
    long long t = idx >> 9;
    int c = t & 15;
    long long nn = t >> 4;
    int n = (int)(nn % NC_);
    int b = (int)(nn / NC_);
    int src_t, src_d;
    if (d < 128) { src_t = n * STR_ + c; src_d = d; }
    else {
        int j = d - 128;
        src_t = n * STR_ + (j & 15);
        src_d = 128 + (j >> 4) * 16 + c;
    }
    clips[idx] = x[((long long)b * L_ + src_t) * D_ + src_d];
}

// ---------------------------------------------------------------------------
// LayerNorm over D=512. One block (256 thr) per row; 2 elems/thread.
// gather=1: input row remapped via clip reconstruction (x_rec fusion),
//           row r -> b=r/L, p=r%L, src=(b*NC+min(p/13,60))*16 + (p-ci*13)
// gstride: per-batch gamma/beta stride (D) or 0 (shared). When gather=0,
//          b = row / rows_per_batch.
// ---------------------------------------------------------------------------
__global__ __launch_bounds__(256) void k_ln(const float* __restrict__ in,
                                            float* __restrict__ out,
                                            const float* __restrict__ gamma,
                                            const float* __restrict__ beta,
                                            int rows_per_batch, int gstride, int gather)
{
    __shared__ float red[8];
    long long row = blockIdx.x;
    long long srow = row;
    int b;
    if (gather) {
        int p = (int)(row % L_);
        b = (int)(row / L_);
        int ci = p / STR_; if (ci > NC_ - 1) ci = NC_ - 1;
        int off = p - ci * STR_;
        srow = ((long long)b * NC_ + ci) * CS_ + off;
    } else {
        b = (int)(row / rows_per_batch);
    }
    const float* xr = in + srow * D_;
    int tid = threadIdx.x;
    float v0 = xr[tid], v1 = xr[tid + 256];
    float s = v0 + v1;
#pragma unroll
    for (int off = 1; off < 64; off <<= 1) s += __shfl_xor(s, off);
    if ((tid & 63) == 0) red[tid >> 6] = s;
    __syncthreads();
    float mean = (red[0] + red[1] + red[2] + red[3]) * (1.0f / 512.0f);
    float d0 = v0 - mean, d1 = v1 - mean;
    float vv = d0 * d0 + d1 * d1;
#pragma unroll
    for (int off = 1; off < 64; off <<= 1) vv += __shfl_xor(vv, off);
    if ((tid & 63) == 0) red[4 + (tid >> 6)] = vv;
    __syncthreads();
    float var = (red[4] + red[5] + red[6] + red[7]) * (1.0f / 512.0f);
    float rstd = rsqrtf(var + 1e-6f);
    const float* g  = gamma + (long long)b * gstride;
    const float* bt = beta  + (long long)b * gstride;
    float* o = out + row * D_;
    o[tid]       = d0 * rstd * g[tid]       + bt[tid];
    o[tid + 256] = d1 * rstd * g[tid + 256] + bt[tid + 256];
}

// ---------------------------------------------------------------------------
// Batched GEMM (fp32): C[z] = op( A[z] @ W[z] (+ bias[z]) ) * alpha (+ res)
// A: (M,K) row-major (row stride K). W: rows K, row stride ldw.
// resmode: 0 none, 1 direct (res + z*sRb + row*N + col), 2 clip-gather from
// res (=x) using the clip/shuffle index map (row -> (n,c), col -> src_d).
// ---------------------------------------------------------------------------
__global__ __launch_bounds__(256) void k_gemm(
    const float* __restrict__ A, const float* __restrict__ W,
    const float* __restrict__ bias, const float* __restrict__ res,
    float* __restrict__ C, int M, int N, int K, int ldw,
    long long sAb, long long sWb, long long sBb, long long sRb, long long sCb,
    float alpha, int relu, int addbias, int resmode)
{
    __shared__ float As_t[16][132];   // [k][m] transposed A tile
    __shared__ float Bs[16][132];     // [k][n]
    int bz = blockIdx.z;
    const float* Ab = A + (long long)bz * sAb;
    const float* Wb = W + (long long)bz * sWb;
    const float* biasb = bias + (long long)bz * sBb;
    float* Cb = C + (long long)bz * sCb;

    int tid = threadIdx.x;
    int row0 = blockIdx.y * 128, col0 = blockIdx.x * 128;
    int tr = tid >> 4, tc = tid & 15;      // 16x16 threads, 8x8 each

    float acc[8][8];
#pragma unroll
    for (int i = 0; i < 8; i++)
#pragma unroll
        for (int j = 0; j < 8; j++) acc[i][j] = 0.f;

    for (int k0 = 0; k0 < K; k0 += 16) {
#pragma unroll
        for (int i = 0; i < 8; i++) {          // A tile: 128x16
            int e = tid + i * 256;
            int r2 = e >> 4, c2 = e & 15;
            int gr = row0 + r2;
            As_t[c2][r2] = (gr < M) ? Ab[(long long)gr * K + k0 + c2] : 0.f;
        }
#pragma unroll
        for (int i = 0; i < 8; i++) {          // B tile: 16x128
            int e = tid + i * 256;
            int rr = e >> 7, cc = e & 127;
            Bs[rr][cc] = Wb[(long long)(k0 + rr) * ldw + col0 + cc];
        }
        __syncthreads();
#pragma unroll
        for (int kk = 0; kk < 16; kk++) {
            const float4 a0 = *(const float4*)&As_t[kk][tr * 8];
            const float4 a1 = *(const float4*)&As_t[kk][tr * 8 + 4];
            const float4 b0 = *(const float4*)&Bs[kk][tc * 8];
            const float4 b1 = *(const float4*)&Bs[kk][tc * 8 + 4];
            float av[8] = {a0.x, a0.y, a0.z, a0.w, a1.x, a1.y, a1.z, a1.w};
            float bv[8] = {b0.x, b0.y, b0.z, b0.w, b1.x, b1.y, b1.z, b1.w};
#pragma unroll
            for (int i = 0; i < 8; i++)
#pragma unroll
                for (int j = 0; j < 8; j++)
                    acc[i][j] = fmaf(av[i], bv[j], acc[i][j]);
        }
        __syncthreads();
    }

#pragma unroll
    for (int i = 0; i < 8; i++) {
        int gr = row0 + tr * 8 + i;
        if (gr >= M) continue;
        long long ro = (long long)gr * N + col0 + tc * 8;
#pragma unroll
        for (int j = 0; j < 8; j++) {
            float v = acc[i][j];
            if (addbias) v += biasb[col0 + tc * 8 + j];
            v *= alpha;
            if (relu) v = fmaxf(v, 0.f);
            if (resmode == 1) {
                v += res[(long long)bz * sRb + ro + j];
            } else if (resmode == 2) {
                int d = col0 + tc * 8 + j;
                int n = gr >> 4, c = gr & 15;
                int src_t, src_d;
                if (d < 128) { src_t = n * STR_ + c; src_d = d; }
                else {
                    int jj = d - 128;
                    src_t = n * STR_ + (jj & 15);
                    src_d = 128 + (jj >> 4) * 16 + c;
                }
                v += res[((long long)bz * L_ + src_t) * D_ + src_d];
            }
            Cb[ro + j] = v;
        }
    }
}

// ---------------------------------------------------------------------------
// Clip attention: one block per (b,n,h). 16x16 scores, softmax, 16x64 ctx.
// q,k,v,ctx layout: (B, NC, CS, D) with d = h*64 + hd. q pre-scaled by 1/8.
// ---------------------------------------------------------------------------
__global__ __launch_bounds__(256) void k_clip_attn(const float* __restrict__ q,
                                                   const float* __restrict__ k,
                                                   const float* __restrict__ v,
                                                   float* __restrict__ ctx)
{
    __shared__ float qs[CS_][65], ks[CS_][65], vs[CS_][65], ps[CS_][17];
    int id = blockIdx.x;
    int h = id & (H_ - 1);
    int n = (id / H_) % NC_;
    int b = id / (H_ * NC_);
    long long base = (((long long)b * NC_ + n) * CS_) * D_ + h * HD_;
    int tid = threadIdx.x;
#pragma unroll
    for (int i = 0; i < 4; i++) {     // 16*64 = 1024 elems per tensor
        int e = tid + i * 256;
        int r = e >> 6, c = e & 63;
        qs[r][c] = q[base + (long long)r * D_ + c];
        ks[r][c] = k[base + (long long)r * D_ + c];
        vs[r][c] = v[base + (long long)r * D_ + c];
    }
    __syncthreads();
    int qr = tid >> 4, kc = tid & 15;
    float s = 0.f;
#pragma unroll
    for (int d = 0; d < HD_; d++) s += qs[qr][d] * ks[kc][d];
    float m = s;
#pragma unroll
    for (int off = 1; off < 16; off <<= 1) m = fmaxf(m, __shfl_xor(m, off));
    float e = __expf(s - m);
    float sum = e;
#pragma unroll
    for (int off = 1; off < 16; off <<= 1) sum += __shfl_xor(sum, off);
    ps[qr][kc] = e / sum;
    __syncthreads();
    int dg = (tid & 15) * 4;
    float o0 = 0, o1 = 0, o2 = 0, o3 = 0;
#pragma unroll
    for (int kk = 0; kk < CS_; kk++) {
        float pp = ps[qr][kk];
        o0 += pp * vs[kk][dg + 0];
        o1 += pp * vs[kk][dg + 1];
        o2 += pp * vs[kk][dg + 2];
        o3 += pp * vs[kk][dg + 3];
    }
    long long ob = base + (long long)qr * D_ + dg;
    *(float4*)&ctx[ob] = make_float4(o0, o1, o2, o3);
}

// ---------------------------------------------------------------------------
// Global flash attention: block per (b,h,qtile64). Online softmax over 13
// k-tiles of 64. q pre-scaled by 1/8. Layout (B,L,D), d = h*64+hd.
// ---------------------------------------------------------------------------
__global__ __launch_bounds__(256) void k_flash(const float* __restrict__ q,
                                               const float* __restrict__ kk_,
                                               const float* __restrict__ vv_,
                                               float* __restrict__ out)
{
    __shared__ float qs[64][68], ks[64][68], vs[64][68], ps[64][65];
    int id = blockIdx.x;
    int qt = id % NQT_;
    int h = (id / NQT_) & (H_ - 1);
    int b = id / (NQT_ * H_);
    int tid = threadIdx.x;
    int q0 = qt * 64;
    long long base = (long long)b * L_ * D_ + h * HD_;
#pragma unroll
    for (int i = 0; i < 16; i++) {
        int e = tid + i * 256;
        int r = e >> 6, c = e & 63;
        int gr = q0 + r;
        qs[r][c] = (gr < L_) ? q[base + (long long)gr * D_ + c] : 0.f;
    }
    int r = tid >> 2, cg = tid & 3;   // 4 threads per q-row, 16 cols each
    float m = -1e30f, l = 0.f;
    float O[16];
#pragma unroll
    for (int j = 0; j < 16; j++) O[j] = 0.f;

    for (int kt = 0; kt < NQT_; kt++) {
        __syncthreads();              // prev PV done with ks/vs/ps
        int k0 = kt * 64;
#pragma unroll
        for (int i = 0; i < 16; i++) {
            int e = tid + i * 256;
            int rr = e >> 6, c = e & 63;
            int gr = k0 + rr;
            bool ok = gr < L_;
            ks[rr][c] = ok ? kk_[base + (long long)gr * D_ + c] : 0.f;
            vs[rr][c] = ok ? vv_[base + (long long)gr * D_ + c] : 0.f;
        }
        __syncthreads();
        float s[16];
#pragma unroll
        for (int j = 0; j < 16; j++) s[j] = 0.f;
        for (int d = 0; d < 64; d += 4) {
            float4 qv = *(const float4*)&qs[r][d];
#pragma unroll
            for (int j = 0; j < 16; j++) {
                float4 kv = *(const float4*)&ks[cg * 16 + j][d];
                s[j] += qv.x * kv.x + qv.y * kv.y + qv.z * kv.z + qv.w * kv.w;
            }
        }
        float mloc = -1e30f;
#pragma unroll
        for (int j = 0; j < 16; j++) {
            if (k0 + cg * 16 + j >= L_) s[j] = -1e30f;
            mloc = fmaxf(mloc, s[j]);
        }
        mloc = fmaxf(mloc, __shfl_xor(mloc, 1));
        mloc = fmaxf(mloc, __shfl_xor(mloc, 2));
        float mnew = fmaxf(m, mloc);
        float scale = __expf(m - mnew);
        float lloc = 0.f;
#pragma unroll
        for (int j = 0; j < 16; j++) { s[j] = __expf(s[j] - mnew); lloc += s[j]; }
        lloc += __shfl_xor(lloc, 1);
        lloc += __shfl_xor(lloc, 2);
        l = l * scale + lloc;
        m = mnew;
#pragma unroll
        for (int j = 0; j < 16; j++) { O[j] *= scale; ps[r][cg * 16 + j] = s[j]; }
        __syncthreads();
        for (int kp = 0; kp < 64; kp++) {
            float pp = ps[r][kp];
#pragma unroll
            for (int jj = 0; jj < 4; jj++) {
                float4 vv = *(const float4*)&vs[kp][cg * 16 + jj * 4];
                O[jj * 4 + 0] += pp * vv.x;
                O[jj * 4 + 1] += pp * vv.y;
                O[jj * 4 + 2] += pp * vv.z;
                O[jj * 4 + 3] += pp * vv.w;
            }
        }
    }
    int gr = q0 + r;
    if (gr < L_) {
        float inv = 1.f / l;
        long long ob = base + (long long)gr * D_ + cg * 16;
#pragma unroll
        for (int jj = 0; jj < 4; jj++) {
            *(float4*)&out[ob + jj * 4] = make_float4(
                O[jj * 4] * inv, O[jj * 4 + 1] * inv,
                O[jj * 4 + 2] * inv, O[jj * 4 + 3] * inv);
        }
    }
}

// ---------------------------------------------------------------------------
static inline void launch_gemm(hipStream_t st, const float* A, const float* W,
                               const float* bias, const float* res, float* C,
                               int M, int N, int K, int ldw, int G,
                               long long sAb, long long sWb, long long sBb,
                               long long sRb, long long sCb,
                               float alpha, int relu, int addbias, int resmode)
{
    dim3 grid(N / 128, (M + 127) / 128, G);
    k_gemm<<<grid, dim3(256), 0, st>>>(A, W, bias, res, C, M, N, K, ldw,
                                       sAb, sWb, sBb, sRb, sCb,
                                       alpha, relu, addbias, resmode);
}

extern "C" void kernel_launch(void* const* d_in, const int* in_sizes, int n_in,
                              void* d_out, int out_size, void* d_ws, size_t ws_size,
                              hipStream_t stream)
{
    (void)in_sizes; (void)n_in; (void)out_size; (void)ws_size;
    const float* x      = (const float*)d_in[0];
    const float* g_ln_g = (const float*)d_in[2];
    const float* g_ln_b = (const float*)d_in[3];
    const float* Wq = (const float*)d_in[4];
    const float* Wk = (const float*)d_in[5];
    const float* Wv = (const float*)d_in[6];
    const float* Wo = (const float*)d_in[7];
    const float* bq = (const float*)d_in[8];
    const float* bk = (const float*)d_in[9];
    const float* bv = (const float*)d_in[10];
    const float* bo = (const float*)d_in[11];
    const float* f_ln_g = (const float*)d_in[12];
    const float* f_ln_b = (const float*)d_in[13];
    const float* W1 = (const float*)d_in[14];
    const float* b1 = (const float*)d_in[15];
    const float* W2 = (const float*)d_in[16];
    const float* b2 = (const float*)d_in[17];
    const float* c_ln_g = (const float*)d_in[18];
    const float* c_ln_b = (const float*)d_in[19];
    const float* cWq = (const float*)d_in[20];
    const float* cWk = (const float*)d_in[21];
    const float* cWv = (const float*)d_in[22];
    const float* cWo = (const float*)d_in[23];
    const float* cbq = (const float*)d_in[24];
    const float* cbk = (const float*)d_in[25];
    const float* cbv = (const float*)d_in[26];
    const float* cbo = (const float*)d_in[27];
    const float* cf_ln_g = (const float*)d_in[28];
    const float* cf_ln_b = (const float*)d_in[29];
    const float* cW1 = (const float*)d_in[30];
    const float* cb1 = (const float*)d_in[31];
    const float* cW2 = (const float*)d_in[32];
    const float* cb2 = (const float*)d_in[33];
    float* out = (float*)d_out;

    const long long SZC = (long long)B_ * NC_ * CS_ * D_;   // 15,990,784 floats
    float* ws = (float*)d_ws;
    float* bA = ws;
    float* bB = bA + SZC;
    float* bC = bB + SZC;
    float* bD = bC + SZC;
    // total workspace: 4 * SZC * 4B = 255.9 MB

    const int MC = MC_;                       // 976 rows per batch (clip path)
    const int MG = B_ * L_;                   // 25472 rows (global path)
    const long long sA  = (long long)MC * D_;          // 499,712
    const long long sW  = (long long)D_ * D_;          // 262,144
    const long long sW1 = (long long)D_ * FF_;         // 1,048,576
    const long long sCh = (long long)MC * 512;         // chunk stride per batch

    // ================= clip path =================
    k_build_clips<<<(int)(SZC / 256), 256, 0, stream>>>(x, bA);
    k_ln<<<B_ * MC, 256, 0, stream>>>(bA, bB, c_ln_g, c_ln_b, MC, D_, 0);
    // q -> bC, k -> bD, v -> bA (clips dead: residual re-gathered from x)
    launch_gemm(stream, bB, cWq, cbq, nullptr, bC, MC, D_, D_, D_, B_,
                sA, sW, D_, 0, sA, 0.125f, 0, 1, 0);
    launch_gemm(stream, bB, cWk, cbk, nullptr, bD, MC, D_, D_, D_, B_,
                sA, sW, D_, 0, sA, 1.0f, 0, 1, 0);
    launch_gemm(stream, bB, cWv, cbv, nullptr, bA, MC, D_, D_, D_, B_,
                sA, sW, D_, 0, sA, 1.0f, 0, 1, 0);
    k_clip_attn<<<B_ * NC_ * H_, 256, 0, stream>>>(bC, bD, bA, bB);   // ctx->bB
    // hcl = ctx@cWo + cbo + clip-gather(x)  -> bC
    launch_gemm(stream, bB, cWo, cbo, x, bC, MC, D_, D_, D_, B_,
                sA, sW, D_, 0, sA, 1.0f, 0, 1, 2);
    k_ln<<<B_ * MC, 256, 0, stream>>>(bC, bB, cf_ln_g, cf_ln_b, MC, D_, 0); // fn->bB
    // FFN chunked over FF (4 x 512): fmid chunk -> bA, clips_out accum -> bD
    for (int c = 0; c < 4; c++) {
        launch_gemm(stream, bB, cW1 + (long long)c * 512, cb1 + (long long)c * 512,
                    nullptr, bA, MC, 512, D_, FF_, B_,
                    sA, sW1, FF_, 0, sCh, 1.0f, 1, 1, 0);
        launch_gemm(stream, bA, cW2 + (long long)c * 512 * D_, cb2,
                    (c == 0) ? bC : bD, bD, MC, D_, 512, D_, B_,
                    sCh, sW1, D_, sA, sA, 1.0f, 0, (c == 0) ? 1 : 0, 1);
    }
    // bD = clips_out

    // ================= global path =================
    // xn = LN(gather(clips_out)) -> bB
    k_ln<<<MG, 256, 0, stream>>>(bD, bB, g_ln_g, g_ln_b, L_, 0, 1);
    launch_gemm(stream, bB, Wq, bq, nullptr, bA, MG, D_, D_, D_, 1,
                0, 0, 0, 0, 0, 0.125f, 0, 1, 0);                 // q2 -> bA
    launch_gemm(stream, bB, Wk, bk, nullptr, bC, MG, D_, D_, D_, 1,
                0, 0, 0, 0, 0, 1.0f, 0, 1, 0);                   // k2 -> bC
    launch_gemm(stream, bB, Wv, bv, nullptr, bD, MG, D_, D_, D_, 1,
                0, 0, 0, 0, 0, 1.0f, 0, 1, 0);                   // v2 -> bD
    k_flash<<<B_ * H_ * NQT_, 256, 0, stream>>>(bA, bC, bD, bB); // ctx2 -> bB
    launch_gemm(stream, bB, Wo, bo, x, bA, MG, D_, D_, D_, 1,
                0, 0, 0, 0, 0, 1.0f, 0, 1, 1);                   // h -> bA
    k_ln<<<MG, 256, 0, stream>>>(bA, bB, f_ln_g, f_ln_b, MG, 0, 0); // hn -> bB
    // FFN2 chunked: mid chunk -> bC, out accum -> d_out (res = h on chunk 0)
    for (int c = 0; c < 4; c++) {
        launch_gemm(stream, bB, W1 + (long long)c * 512, b1 + (long long)c * 512,
                    nullptr, bC, MG, 512, D_, FF_, 1,
                    0, 0, 0, 0, 0, 1.0f, 1, 1, 0);
        launch_gemm(stream, bC, W2 + (long long)c * 512 * D_, b2,
                    (c == 0) ? bA : out, out, MG, D_, 512, D_, 1,
                    0, 0, 0, 0, 0, 1.0f, 0, (c == 0) ? 1 : 0, 1);
    }
}

// Round 3
// 4487.466 us; speedup vs baseline: 2.1094x; 2.1094x over previous
//
#include <hip/hip_runtime.h>

#define B_   32
#define L_   796
#define D_   512
#define H_   8
#define HD_  64
#define FF_  2048
#define CS_  16
#define STR_ 13
#define NC_  61
#define NQT_ 13
#define MC_  976   // NC_*CS_ rows per batch (clip path)

typedef __attribute__((ext_vector_type(8))) short short8;
typedef __attribute__((ext_vector_type(4))) float f32x4;

__device__ __forceinline__ unsigned short f2bf(float x) {
    unsigned u = __float_as_uint(x);
    unsigned r = u + 0x7FFFu + ((u >> 16) & 1u);   // RNE
    return (unsigned short)(r >> 16);
}
__device__ __forceinline__ float bf2f(unsigned short h) {
    return __uint_as_float(((unsigned)h) << 16);
}

// ---------------------------------------------------------------------------
// build clips (f32): gather windows + channel shuffle
// ---------------------------------------------------------------------------
__global__ __launch_bounds__(256) void k_build_clips(const float* __restrict__ x,
                                                     float* __restrict__ clips)
{
    long long idx = (long long)blockIdx.x * 256 + threadIdx.x;   // B*NC*CS*D
    int d = idx & 511;
    long long t = idx >> 9;
    int c = t & 15;
    long long nn = t >> 4;
    int n = (int)(nn % NC_);
    int b = (int)(nn / NC_);
    int src_t, src_d;
    if (d < 128) { src_t = n * STR_ + c; src_d = d; }
    else {
        int j = d - 128;
        src_t = n * STR_ + (j & 15);
        src_d = 128 + (j >> 4) * 16 + c;
    }
    clips[idx] = x[((long long)b * L_ + src_t) * D_ + src_d];
}

// ---------------------------------------------------------------------------
// LayerNorm D=512, f32 in -> bf16 out. gather=1: clip-reconstruction row remap.
// ---------------------------------------------------------------------------
__global__ __launch_bounds__(256) void k_ln(const float* __restrict__ in,
                                            unsigned short* __restrict__ out,
                                            const float* __restrict__ gamma,
                                            const float* __restrict__ beta,
                                            int rows_per_batch, int gstride, int gather)
{
    __shared__ float red[8];
    long long row = blockIdx.x;
    long long srow = row;
    int b;
    if (gather) {
        int p = (int)(row % L_);
        b = (int)(row / L_);
        int ci = p / STR_; if (ci > NC_ - 1) ci = NC_ - 1;
        int off = p - ci * STR_;
        srow = ((long long)b * NC_ + ci) * CS_ + off;
    } else {
        b = (int)(row / rows_per_batch);
    }
    const float* xr = in + srow * D_;
    int tid = threadIdx.x;
    float v0 = xr[tid], v1 = xr[tid + 256];
    float s = v0 + v1;
#pragma unroll
    for (int off = 1; off < 64; off <<= 1) s += __shfl_xor(s, off);
    if ((tid & 63) == 0) red[tid >> 6] = s;
    __syncthreads();
    float mean = (red[0] + red[1] + red[2] + red[3]) * (1.0f / 512.0f);
    float d0 = v0 - mean, d1 = v1 - mean;
    float vv = d0 * d0 + d1 * d1;
#pragma unroll
    for (int off = 1; off < 64; off <<= 1) vv += __shfl_xor(vv, off);
    if ((tid & 63) == 0) red[4 + (tid >> 6)] = vv;
    __syncthreads();
    float var = (red[4] + red[5] + red[6] + red[7]) * (1.0f / 512.0f);
    float rstd = rsqrtf(var + 1e-6f);
    const float* g  = gamma + (long long)b * gstride;
    const float* bt = beta  + (long long)b * gstride;
    unsigned short* o = out + row * D_;
    o[tid]       = f2bf(d0 * rstd * g[tid]       + bt[tid]);
    o[tid + 256] = f2bf(d1 * rstd * g[tid + 256] + bt[tid + 256]);
}

// ---------------------------------------------------------------------------
// Weight transpose+convert: W (f32, K=512 rows x 512 cols, row stride rowStride)
// -> WT (bf16, [512 n][512 k]). grid (16,16,G).
// ---------------------------------------------------------------------------
__global__ __launch_bounds__(256) void k_wt(const float* __restrict__ W,
                                            unsigned short* __restrict__ T,
                                            int rowStride, long long sWb, long long sTb)
{
    __shared__ float t[32][33];
    int z = blockIdx.z;
    const float* Wz = W + (long long)z * sWb;
    unsigned short* Tz = T + (long long)z * sTb;
    int n0 = blockIdx.x << 5, k0 = blockIdx.y << 5;
    int tx = threadIdx.x & 31, ty = threadIdx.x >> 5;
#pragma unroll
    for (int i = 0; i < 4; i++) {
        int k = ty + (i << 3);
        t[k][tx] = Wz[(long long)(k0 + k) * rowStride + n0 + tx];
    }
    __syncthreads();
#pragma unroll
    for (int i = 0; i < 4; i++) {
        int n = ty + (i << 3);
        Tz[(long long)(n0 + n) * 512 + k0 + tx] = f2bf(t[tx][n]);
    }
}

// ---------------------------------------------------------------------------
// bf16 MFMA GEMM: C[z] = op( A[z] @ WT[z]^T (+bias) )*alpha (+res)
// A: [M][K] bf16 row-major (k-contig). WT: [N][K] bf16 (k-contig).
// 128x128 tile, BK=64, 4 waves x (64x64), mfma_f32_16x16x32_bf16.
// LDS XOR-swizzle: 16B slot s at row r stored at s^(r&7)  (T2).
// resmode: 0 none; 1 res[z*sRb + gr*N + gc] (f32); 2 clip-gather from xg.
// outbf16: 1 -> bf16 store, 0 -> f32 store.
// ---------------------------------------------------------------------------
__global__ __launch_bounds__(256) void k_gemm_mfma(
    const unsigned short* __restrict__ A, const unsigned short* __restrict__ WT,
    const float* __restrict__ bias, const float* __restrict__ res,
    const float* __restrict__ xg, void* __restrict__ Cout,
    int M, int N, int K,
    long long sAb, long long sWb, long long sBb, long long sRb, long long sCb,
    float alpha, int relu, int addbias, int resmode, int outbf16)
{
    __shared__ unsigned short lds[16384];      // 32 KB: A tile + W tile
    unsigned short* lA = lds;
    unsigned short* lW = lds + 8192;
    int tid = threadIdx.x;
    int z = blockIdx.z;
    int row0 = blockIdx.y << 7, col0 = blockIdx.x << 7;
    const unsigned short* Ab = A + z * sAb;
    const unsigned short* Wb = WT + z * sWb;

    int w = tid >> 6, lane = tid & 63;
    int wr = (w >> 1) << 6, wc = (w & 1) << 6;
    int l15 = lane & 15, lg = lane >> 4;

    f32x4 acc[4][4];
#pragma unroll
    for (int i = 0; i < 4; i++)
#pragma unroll
        for (int j = 0; j < 4; j++) acc[i][j] = (f32x4)0.f;

    int sr = tid & 127;            // staging row
    int kh = (tid >> 7) << 5;      // 0 or 32 (k-half)
    int mrem = M - row0;
    int sx = (sr & 7);             // row swizzle key
    int rb = sr << 6;              // LDS row base (elements)

    for (int k0 = 0; k0 < K; k0 += 64) {
        const unsigned short* As = Ab + (long long)(row0 + sr) * K + k0 + kh;
        const unsigned short* Ws = Wb + (long long)(col0 + sr) * K + k0 + kh;
        bool aok = sr < mrem;
        short8 av0 = aok ? *(const short8*)(As)      : (short8)0;
        short8 av1 = aok ? *(const short8*)(As + 8)  : (short8)0;
        short8 av2 = aok ? *(const short8*)(As + 16) : (short8)0;
        short8 av3 = aok ? *(const short8*)(As + 24) : (short8)0;
        short8 wv0 = *(const short8*)(Ws);
        short8 wv1 = *(const short8*)(Ws + 8);
        short8 wv2 = *(const short8*)(Ws + 16);
        short8 wv3 = *(const short8*)(Ws + 24);
        __syncthreads();           // prior-iter LDS reads done
        int kb = kh >> 3;
        *(short8*)(lA + rb + (((kb + 0) ^ sx) << 3)) = av0;
        *(short8*)(lA + rb + (((kb + 1) ^ sx) << 3)) = av1;
        *(short8*)(lA + rb + (((kb + 2) ^ sx) << 3)) = av2;
        *(short8*)(lA + rb + (((kb + 3) ^ sx) << 3)) = av3;
        *(short8*)(lW + rb + (((kb + 0) ^ sx) << 3)) = wv0;
        *(short8*)(lW + rb + (((kb + 1) ^ sx) << 3)) = wv1;
        *(short8*)(lW + rb + (((kb + 2) ^ sx) << 3)) = wv2;
        *(short8*)(lW + rb + (((kb + 3) ^ sx) << 3)) = wv3;
        __syncthreads();
#pragma unroll
        for (int ks = 0; ks < 2; ks++) {
            short8 af[4], bfr[4];
#pragma unroll
            for (int mf = 0; mf < 4; mf++) {
                int r = wr + (mf << 4) + l15;
                int slot = ((ks << 2) + lg) ^ (r & 7);
                af[mf] = *(const short8*)(lA + (r << 6) + (slot << 3));
            }
#pragma unroll
            for (int nf = 0; nf < 4; nf++) {
                int r = wc + (nf << 4) + l15;
                int slot = ((ks << 2) + lg) ^ (r & 7);
                bfr[nf] = *(const short8*)(lW + (r << 6) + (slot << 3));
            }
#pragma unroll
            for (int mf = 0; mf < 4; mf++)
#pragma unroll
                for (int nf = 0; nf < 4; nf++)
                    acc[mf][nf] = __builtin_amdgcn_mfma_f32_16x16x32_bf16(
                        af[mf], bfr[nf], acc[mf][nf], 0, 0, 0);
        }
    }

    const float* bz = bias + z * sBb;
#pragma unroll
    for (int mf = 0; mf < 4; mf++) {
#pragma unroll
        for (int reg = 0; reg < 4; reg++) {
            int gr = row0 + wr + (mf << 4) + (lg << 2) + reg;
            if (gr >= M) continue;
#pragma unroll
            for (int nf = 0; nf < 4; nf++) {
                int gc = col0 + wc + (nf << 4) + l15;
                float v = acc[mf][nf][reg];
                if (addbias) v += bz[gc];
                v *= alpha;
                if (relu) v = fmaxf(v, 0.f);
                if (resmode == 1) {
                    v += res[z * sRb + (long long)gr * N + gc];
                } else if (resmode == 2) {
                    int n = gr >> 4, c = gr & 15;
                    int st, sd;
                    if (gc < 128) { st = n * STR_ + c; sd = gc; }
                    else {
                        int jj = gc - 128;
                        st = n * STR_ + (jj & 15);
                        sd = 128 + ((jj >> 4) << 4) + c;
                    }
                    v += xg[((long long)z * L_ + st) * D_ + sd];
                }
                long long co = z * sCb + (long long)gr * N + gc;
                if (outbf16) ((unsigned short*)Cout)[co] = f2bf(v);
                else         ((float*)Cout)[co] = v;
            }
        }
    }
}

// ---------------------------------------------------------------------------
// Clip attention (bf16 io, f32 math): block per (b,n,h). 16x16 scores.
// ---------------------------------------------------------------------------
__global__ __launch_bounds__(256) void k_clip_attn(const unsigned short* __restrict__ q,
                                                   const unsigned short* __restrict__ k,
                                                   const unsigned short* __restrict__ v,
                                                   unsigned short* __restrict__ ctx)
{
    __shared__ float qs[CS_][65], ks[CS_][65], vs[CS_][65], ps[CS_][17];
    int id = blockIdx.x;
    int h = id & (H_ - 1);
    int n = (id / H_) % NC_;
    int b = id / (H_ * NC_);
    long long base = (((long long)b * NC_ + n) * CS_) * D_ + h * HD_;
    int tid = threadIdx.x;
#pragma unroll
    for (int i = 0; i < 4; i++) {
        int e = tid + i * 256;
        int r = e >> 6, c = e & 63;
        qs[r][c] = bf2f(q[base + (long long)r * D_ + c]);
        ks[r][c] = bf2f(k[base + (long long)r * D_ + c]);
        vs[r][c] = bf2f(v[base + (long long)r * D_ + c]);
    }
    __syncthreads();
    int qr = tid >> 4, kc = tid & 15;
    float s = 0.f;
#pragma unroll
    for (int d = 0; d < HD_; d++) s += qs[qr][d] * ks[kc][d];
    float m = s;
#pragma unroll
    for (int off = 1; off < 16; off <<= 1) m = fmaxf(m, __shfl_xor(m, off));
    float e = __expf(s - m);
    float sum = e;
#pragma unroll
    for (int off = 1; off < 16; off <<= 1) sum += __shfl_xor(sum, off);
    ps[qr][kc] = e / sum;
    __syncthreads();
    int dg = (tid & 15) * 4;
    float o0 = 0, o1 = 0, o2 = 0, o3 = 0;
#pragma unroll
    for (int kk = 0; kk < CS_; kk++) {
        float pp = ps[qr][kk];
        o0 += pp * vs[kk][dg + 0];
        o1 += pp * vs[kk][dg + 1];
        o2 += pp * vs[kk][dg + 2];
        o3 += pp * vs[kk][dg + 3];
    }
    long long ob = base + (long long)qr * D_ + dg;
    ctx[ob + 0] = f2bf(o0);
    ctx[ob + 1] = f2bf(o1);
    ctx[ob + 2] = f2bf(o2);
    ctx[ob + 3] = f2bf(o3);
}

// ---------------------------------------------------------------------------
// Global flash attention (bf16 io, f32 math). block per (b,h,qtile64).
// cg-staggered LDS access to cut 4-way bank conflicts to 2-way.
// ---------------------------------------------------------------------------
__global__ __launch_bounds__(256) void k_flash(const unsigned short* __restrict__ q,
                                               const unsigned short* __restrict__ kk_,
                                               const unsigned short* __restrict__ vv_,
                                               unsigned short* __restrict__ out)
{
    __shared__ float qs[64][68], ks[64][68], vs[64][68], ps[64][65];
    int id = blockIdx.x;
    int qt = id % NQT_;
    int h = (id / NQT_) & (H_ - 1);
    int b = id / (NQT_ * H_);
    int tid = threadIdx.x;
    int q0 = qt * 64;
    long long base = (long long)b * L_ * D_ + h * HD_;
#pragma unroll
    for (int i = 0; i < 16; i++) {
        int e = tid + i * 256;
        int r = e >> 6, c = e & 63;
        int gr = q0 + r;
        qs[r][c] = (gr < L_) ? bf2f(q[base + (long long)gr * D_ + c]) : 0.f;
    }
    int r = tid >> 2, cg = tid & 3;
    float m = -1e30f, l = 0.f;
    float O[16];
#pragma unroll
    for (int j = 0; j < 16; j++) O[j] = 0.f;

    for (int kt = 0; kt < NQT_; kt++) {
        __syncthreads();
        int k0 = kt * 64;
#pragma unroll
        for (int i = 0; i < 16; i++) {
            int e = tid + i * 256;
            int rr = e >> 6, c = e & 63;
            int gr = k0 + rr;
            bool ok = gr < L_;
            ks[rr][c] = ok ? bf2f(kk_[base + (long long)gr * D_ + c]) : 0.f;
            vs[rr][c] = ok ? bf2f(vv_[base + (long long)gr * D_ + c]) : 0.f;
        }
        __syncthreads();
        float s[16];
#pragma unroll
        for (int j = 0; j < 16; j++) s[j] = 0.f;
#pragma unroll
        for (int dstep = 0; dstep < 16; dstep++) {
            int d = ((dstep << 2) + (cg << 4)) & 63;      // cg-staggered
            float4 qv = *(const float4*)&qs[r][d];
#pragma unroll
            for (int j = 0; j < 16; j++) {
                float4 kv = *(const float4*)&ks[(cg << 4) + j][d];
                s[j] += qv.x * kv.x + qv.y * kv.y + qv.z * kv.z + qv.w * kv.w;
            }
        }
        float mloc = -1e30f;
#pragma unroll
        for (int j = 0; j < 16; j++) {
            if (k0 + (cg << 4) + j >= L_) s[j] = -1e30f;
            mloc = fmaxf(mloc, s[j]);
        }
        mloc = fmaxf(mloc, __shfl_xor(mloc, 1));
        mloc = fmaxf(mloc, __shfl_xor(mloc, 2));
        float mnew = fmaxf(m, mloc);
        float scale = __expf(m - mnew);
        float lloc = 0.f;
#pragma unroll
        for (int j = 0; j < 16; j++) { s[j] = __expf(s[j] - mnew); lloc += s[j]; }
        lloc += __shfl_xor(lloc, 1);
        lloc += __shfl_xor(lloc, 2);
        l = l * scale + lloc;
        m = mnew;
#pragma unroll
        for (int j = 0; j < 16; j++) { O[j] *= scale; ps[r][(cg << 4) + j] = s[j]; }
        __syncthreads();
        for (int kp = 0; kp < 64; kp++) {
            int kpp = (kp + (cg << 4)) & 63;              // cg-staggered token
            float pp = ps[r][kpp];
#pragma unroll
            for (int jj = 0; jj < 4; jj++) {
                float4 vv = *(const float4*)&vs[kpp][(cg << 4) + (jj << 2)];
                O[jj * 4 + 0] += pp * vv.x;
                O[jj * 4 + 1] += pp * vv.y;
                O[jj * 4 + 2] += pp * vv.z;
                O[jj * 4 + 3] += pp * vv.w;
            }
        }
    }
    int gr = q0 + r;
    if (gr < L_) {
        float inv = 1.f / l;
        long long ob = base + (long long)gr * D_ + (cg << 4);
#pragma unroll
        for (int j = 0; j < 16; j++) out[ob + j] = f2bf(O[j] * inv);
    }
}

// ---------------------------------------------------------------------------
static inline void gemm(hipStream_t st, const unsigned short* A, const unsigned short* WTp,
                        const float* bias, const float* res, const float* xg, void* C,
                        int M, int N, int K, int G,
                        long long sAb, long long sWb, long long sBb,
                        long long sRb, long long sCb,
                        float alpha, int relu, int addbias, int resmode, int outbf16)
{
    dim3 grid(N / 128, (M + 127) / 128, G);
    k_gemm_mfma<<<grid, 256, 0, st>>>(A, WTp, bias, res, xg, C, M, N, K,
                                      sAb, sWb, sBb, sRb, sCb,
                                      alpha, relu, addbias, resmode, outbf16);
}
static inline void wt(hipStream_t st, const float* W, unsigned short* T,
                      int rowStride, long long sWb, long long sTb, int G)
{
    k_wt<<<dim3(16, 16, G), 256, 0, st>>>(W, T, rowStride, sWb, sTb);
}

extern "C" void kernel_launch(void* const* d_in, const int* in_sizes, int n_in,
                              void* d_out, int out_size, void* d_ws, size_t ws_size,
                              hipStream_t stream)
{
    (void)in_sizes; (void)n_in; (void)out_size; (void)ws_size;
    const float* x      = (const float*)d_in[0];
    const float* g_ln_g = (const float*)d_in[2];
    const float* g_ln_b = (const float*)d_in[3];
    const float* Wq = (const float*)d_in[4];
    const float* Wk = (const float*)d_in[5];
    const float* Wv = (const float*)d_in[6];
    const float* Wo = (const float*)d_in[7];
    const float* bq = (const float*)d_in[8];
    const float* bk = (const float*)d_in[9];
    const float* bv = (const float*)d_in[10];
    const float* bo = (const float*)d_in[11];
    const float* f_ln_g = (const float*)d_in[12];
    const float* f_ln_b = (const float*)d_in[13];
    const float* W1 = (const float*)d_in[14];
    const float* b1 = (const float*)d_in[15];
    const float* W2 = (const float*)d_in[16];
    const float* b2 = (const float*)d_in[17];
    const float* c_ln_g = (const float*)d_in[18];
    const float* c_ln_b = (const float*)d_in[19];
    const float* cWq = (const float*)d_in[20];
    const float* cWk = (const float*)d_in[21];
    const float* cWv = (const float*)d_in[22];
    const float* cWo = (const float*)d_in[23];
    const float* cbq = (const float*)d_in[24];
    const float* cbk = (const float*)d_in[25];
    const float* cbv = (const float*)d_in[26];
    const float* cbo = (const float*)d_in[27];
    const float* cf_ln_g = (const float*)d_in[28];
    const float* cf_ln_b = (const float*)d_in[29];
    const float* cW1 = (const float*)d_in[30];
    const float* cb1 = (const float*)d_in[31];
    const float* cW2 = (const float*)d_in[32];
    const float* cb2 = (const float*)d_in[33];

    // workspace layout (bytes): 209 MB total
    char* wsb = (char*)d_ws;
    float*          bA = (float*)wsb;                               // 64MB f32: clips -> hcl -> h
    unsigned short* bB = (unsigned short*)(wsb + (64ll  << 20));    // 32MB bf16: LN outs / ctx
    unsigned short* bQ = (unsigned short*)(wsb + (96ll  << 20));    // 32MB bf16
    unsigned short* bK = (unsigned short*)(wsb + (128ll << 20));    // 32MB bf16
    unsigned short* bV = (unsigned short*)(wsb + (160ll << 20));    // 32MB bf16 (also fmid chunks)
    unsigned short* wT = (unsigned short*)(wsb + (192ll << 20));    // 17MB bf16 W^T scratch
    float*          CO = (float*)(wsb + (96ll << 20));              // clips_out f32 (overlays bQ+bK)

    const long long SZC = (long long)B_ * MC_ * D_;
    const long long sA  = (long long)MC_ * D_;       // per-batch A stride (clip)
    const long long sWW = (long long)D_ * D_;        // 512*512 (WT batch stride)
    const int MG = B_ * L_;

    // ================= clip path =================
    k_build_clips<<<(int)(SZC / 256), 256, 0, stream>>>(x, bA);
    k_ln<<<B_ * MC_, 256, 0, stream>>>(bA, bB, c_ln_g, c_ln_b, MC_, D_, 0);
    wt(stream, cWq, wT, D_, sWW, sWW, B_);
    gemm(stream, bB, wT, cbq, nullptr, nullptr, bQ, MC_, D_, D_, B_,
         sA, sWW, D_, 0, sA, 0.125f, 0, 1, 0, 1);
    wt(stream, cWk, wT, D_, sWW, sWW, B_);
    gemm(stream, bB, wT, cbk, nullptr, nullptr, bK, MC_, D_, D_, B_,
         sA, sWW, D_, 0, sA, 1.0f, 0, 1, 0, 1);
    wt(stream, cWv, wT, D_, sWW, sWW, B_);
    gemm(stream, bB, wT, cbv, nullptr, nullptr, bV, MC_, D_, D_, B_,
         sA, sWW, D_, 0, sA, 1.0f, 0, 1, 0, 1);
    k_clip_attn<<<B_ * NC_ * H_, 256, 0, stream>>>(bQ, bK, bV, bB);      // ctx -> bB
    wt(stream, cWo, wT, D_, sWW, sWW, B_);
    gemm(stream, bB, wT, cbo, nullptr, x, bA, MC_, D_, D_, B_,
         sA, sWW, D_, 0, sA, 1.0f, 0, 1, 2, 0);                          // hcl f32 -> bA
    k_ln<<<B_ * MC_, 256, 0, stream>>>(bA, bB, cf_ln_g, cf_ln_b, MC_, D_, 0);
    for (int c = 0; c < 4; c++) {   // FFN chunked over FF (4 x 512)
        wt(stream, cW1 + c * 512, wT, FF_, (long long)D_ * FF_, sWW, B_);
        gemm(stream, bB, wT, cb1 + c * 512, nullptr, nullptr, bV, MC_, 512, D_, B_,
             sA, sWW, FF_, 0, sA, 1.0f, 1, 1, 0, 1);                     // fmid chunk (relu)
        wt(stream, cW2 + (long long)c * 512 * D_, wT, D_, (long long)FF_ * D_, sWW, B_);
        gemm(stream, bV, wT, cb2, (c == 0) ? bA : CO, nullptr, CO, MC_, D_, 512, B_,
             sA, sWW, D_, sA, sA, 1.0f, 0, (c == 0) ? 1 : 0, 1, 0);      // clips_out f32
    }

    // ================= global path =================
    k_ln<<<MG, 256, 0, stream>>>(CO, bB, g_ln_g, g_ln_b, L_, 0, 1);      // xn (gathered)
    wt(stream, Wq, wT, D_, 0, 0, 1);
    gemm(stream, bB, wT, bq, nullptr, nullptr, bQ, MG, D_, D_, 1,
         0, 0, 0, 0, 0, 0.125f, 0, 1, 0, 1);
    wt(stream, Wk, wT, D_, 0, 0, 1);
    gemm(stream, bB, wT, bk, nullptr, nullptr, bK, MG, D_, D_, 1,
         0, 0, 0, 0, 0, 1.0f, 0, 1, 0, 1);
    wt(stream, Wv, wT, D_, 0, 0, 1);
    gemm(stream, bB, wT, bv, nullptr, nullptr, bV, MG, D_, D_, 1,
         0, 0, 0, 0, 0, 1.0f, 0, 1, 0, 1);
    k_flash<<<B_ * H_ * NQT_, 256, 0, stream>>>(bQ, bK, bV, bB);         // ctx2 -> bB
    wt(stream, Wo, wT, D_, 0, 0, 1);
    gemm(stream, bB, wT, bo, x, nullptr, bA, MG, D_, D_, 1,
         0, 0, 0, 0, 0, 1.0f, 0, 1, 1, 0);                               // h f32 -> bA
    k_ln<<<MG, 256, 0, stream>>>(bA, bB, f_ln_g, f_ln_b, MG, 0, 0);      // hn
    for (int c = 0; c < 4; c++) {
        wt(stream, W1 + c * 512, wT, FF_, 0, 0, 1);
        gemm(stream, bB, wT, b1 + c * 512, nullptr, nullptr, bV, MG, 512, D_, 1,
             0, 0, 0, 0, 0, 1.0f, 1, 1, 0, 1);                           // mid2 chunk
        wt(stream, W2 + (long long)c * 512 * D_, wT, D_, 0, 0, 1);
        gemm(stream, bV, wT, b2, (c == 0) ? bA : (float*)d_out, nullptr, d_out,
             MG, D_, 512, 1, 0, 0, 0, 0, 0, 1.0f, 0, (c == 0) ? 1 : 0, 1, 0);
    }
}

// Round 4
// 2612.387 us; speedup vs baseline: 3.6234x; 1.7178x over previous
//
#include <hip/hip_runtime.h>

#define B_   32
#define L_   796
#define D_   512
#define H_   8
#define HD_  64
#define FF_  2048
#define CS_  16
#define STR_ 13
#define NC_  61
#define NQT_ 13
#define MC_  976   // NC_*CS_ rows per batch (clip path)

typedef __attribute__((ext_vector_type(8))) short short8;
typedef __attribute__((ext_vector_type(4))) float f32x4;

__device__ __forceinline__ unsigned short f2bf(float x) {
    unsigned u = __float_as_uint(x);
    unsigned r = u + 0x7FFFu + ((u >> 16) & 1u);   // RNE
    return (unsigned short)(r >> 16);
}
__device__ __forceinline__ float bf2f(unsigned short h) {
    return __uint_as_float(((unsigned)h) << 16);
}

// ---------------------------------------------------------------------------
// build clips (f32): gather windows + channel shuffle
// ---------------------------------------------------------------------------
__global__ __launch_bounds__(256) void k_build_clips(const float* __restrict__ x,
                                                     float* __restrict__ clips)
{
    long long idx = (long long)blockIdx.x * 256 + threadIdx.x;   // B*NC*CS*D
    int d = idx & 511;
    long long t = idx >> 9;
    int c = t & 15;
    long long nn = t >> 4;
    int n = (int)(nn % NC_);
    int b = (int)(nn / NC_);
    int src_t, src_d;
    if (d < 128) { src_t = n * STR_ + c; src_d = d; }
    else {
        int j = d - 128;
        src_t = n * STR_ + (j & 15);
        src_d = 128 + (j >> 4) * 16 + c;
    }
    clips[idx] = x[((long long)b * L_ + src_t) * D_ + src_d];
}

// ---------------------------------------------------------------------------
// LayerNorm D=512, f32 in -> bf16 out. gather=1: clip-reconstruction row remap.
// ---------------------------------------------------------------------------
__global__ __launch_bounds__(256) void k_ln(const float* __restrict__ in,
                                            unsigned short* __restrict__ out,
                                            const float* __restrict__ gamma,
                                            const float* __restrict__ beta,
                                            int rows_per_batch, int gstride, int gather)
{
    __shared__ float red[8];
    long long row = blockIdx.x;
    long long srow = row;
    int b;
    if (gather) {
        int p = (int)(row % L_);
        b = (int)(row / L_);
        int ci = p / STR_; if (ci > NC_ - 1) ci = NC_ - 1;
        int off = p - ci * STR_;
        srow = ((long long)b * NC_ + ci) * CS_ + off;
    } else {
        b = (int)(row / rows_per_batch);
    }
    const float* xr = in + srow * D_;
    int tid = threadIdx.x;
    float v0 = xr[tid], v1 = xr[tid + 256];
    float s = v0 + v1;
#pragma unroll
    for (int off = 1; off < 64; off <<= 1) s += __shfl_xor(s, off);
    if ((tid & 63) == 0) red[tid >> 6] = s;
    __syncthreads();
    float mean = (red[0] + red[1] + red[2] + red[3]) * (1.0f / 512.0f);
    float d0 = v0 - mean, d1 = v1 - mean;
    float vv = d0 * d0 + d1 * d1;
#pragma unroll
    for (int off = 1; off < 64; off <<= 1) vv += __shfl_xor(vv, off);
    if ((tid & 63) == 0) red[4 + (tid >> 6)] = vv;
    __syncthreads();
    float var = (red[4] + red[5] + red[6] + red[7]) * (1.0f / 512.0f);
    float rstd = rsqrtf(var + 1e-6f);
    const float* g  = gamma + (long long)b * gstride;
    const float* bt = beta  + (long long)b * gstride;
    unsigned short* o = out + row * D_;
    o[tid]       = f2bf(d0 * rstd * g[tid]       + bt[tid]);
    o[tid + 256] = f2bf(d1 * rstd * g[tid + 256] + bt[tid + 256]);
}

// ---------------------------------------------------------------------------
// Weight transpose+convert: W (f32, 512 x 512 view, row stride rowStride)
// -> WT (bf16, [512 n][512 k]). grid (16,16,G).
// ---------------------------------------------------------------------------
__global__ __launch_bounds__(256) void k_wt(const float* __restrict__ W,
                                            unsigned short* __restrict__ T,
                                            int rowStride, long long sWb, long long sTb)
{
    __shared__ float t[32][33];
    int z = blockIdx.z;
    const float* Wz = W + (long long)z * sWb;
    unsigned short* Tz = T + (long long)z * sTb;
    int n0 = blockIdx.x << 5, k0 = blockIdx.y << 5;
    int tx = threadIdx.x & 31, ty = threadIdx.x >> 5;
#pragma unroll
    for (int i = 0; i < 4; i++) {
        int k = ty + (i << 3);
        t[k][tx] = Wz[(long long)(k0 + k) * rowStride + n0 + tx];
    }
    __syncthreads();
#pragma unroll
    for (int i = 0; i < 4; i++) {
        int n = ty + (i << 3);
        Tz[(long long)(n0 + n) * 512 + k0 + tx] = f2bf(t[tx][n]);
    }
}

// ---------------------------------------------------------------------------
// bf16 MFMA GEMM (unchanged from round 3, verified)
// ---------------------------------------------------------------------------
__global__ __launch_bounds__(256) void k_gemm_mfma(
    const unsigned short* __restrict__ A, const unsigned short* __restrict__ WT,
    const float* __restrict__ bias, const float* __restrict__ res,
    const float* __restrict__ xg, void* __restrict__ Cout,
    int M, int N, int K,
    long long sAb, long long sWb, long long sBb, long long sRb, long long sCb,
    float alpha, int relu, int addbias, int resmode, int outbf16)
{
    __shared__ unsigned short lds[16384];      // 32 KB: A tile + W tile
    unsigned short* lA = lds;
    unsigned short* lW = lds + 8192;
    int tid = threadIdx.x;
    int z = blockIdx.z;
    int row0 = blockIdx.y << 7, col0 = blockIdx.x << 7;
    const unsigned short* Ab = A + z * sAb;
    const unsigned short* Wb = WT + z * sWb;

    int w = tid >> 6, lane = tid & 63;
    int wr = (w >> 1) << 6, wc = (w & 1) << 6;
    int l15 = lane & 15, lg = lane >> 4;

    f32x4 acc[4][4];
#pragma unroll
    for (int i = 0; i < 4; i++)
#pragma unroll
        for (int j = 0; j < 4; j++) acc[i][j] = (f32x4)0.f;

    int sr = tid & 127;            // staging row
    int kh = (tid >> 7) << 5;      // 0 or 32 (k-half)
    int mrem = M - row0;
    int sx = (sr & 7);             // row swizzle key
    int rb = sr << 6;              // LDS row base (elements)

    for (int k0 = 0; k0 < K; k0 += 64) {
        const unsigned short* As = Ab + (long long)(row0 + sr) * K + k0 + kh;
        const unsigned short* Ws = Wb + (long long)(col0 + sr) * K + k0 + kh;
        bool aok = sr < mrem;
        short8 av0 = aok ? *(const short8*)(As)      : (short8)0;
        short8 av1 = aok ? *(const short8*)(As + 8)  : (short8)0;
        short8 av2 = aok ? *(const short8*)(As + 16) : (short8)0;
        short8 av3 = aok ? *(const short8*)(As + 24) : (short8)0;
        short8 wv0 = *(const short8*)(Ws);
        short8 wv1 = *(const short8*)(Ws + 8);
        short8 wv2 = *(const short8*)(Ws + 16);
        short8 wv3 = *(const short8*)(Ws + 24);
        __syncthreads();           // prior-iter LDS reads done
        int kb = kh >> 3;
        *(short8*)(lA + rb + (((kb + 0) ^ sx) << 3)) = av0;
        *(short8*)(lA + rb + (((kb + 1) ^ sx) << 3)) = av1;
        *(short8*)(lA + rb + (((kb + 2) ^ sx) << 3)) = av2;
        *(short8*)(lA + rb + (((kb + 3) ^ sx) << 3)) = av3;
        *(short8*)(lW + rb + (((kb + 0) ^ sx) << 3)) = wv0;
        *(short8*)(lW + rb + (((kb + 1) ^ sx) << 3)) = wv1;
        *(short8*)(lW + rb + (((kb + 2) ^ sx) << 3)) = wv2;
        *(short8*)(lW + rb + (((kb + 3) ^ sx) << 3)) = wv3;
        __syncthreads();
#pragma unroll
        for (int ks = 0; ks < 2; ks++) {
            short8 af[4], bfr[4];
#pragma unroll
            for (int mf = 0; mf < 4; mf++) {
                int r = wr + (mf << 4) + l15;
                int slot = ((ks << 2) + lg) ^ (r & 7);
                af[mf] = *(const short8*)(lA + (r << 6) + (slot << 3));
            }
#pragma unroll
            for (int nf = 0; nf < 4; nf++) {
                int r = wc + (nf << 4) + l15;
                int slot = ((ks << 2) + lg) ^ (r & 7);
                bfr[nf] = *(const short8*)(lW + (r << 6) + (slot << 3));
            }
#pragma unroll
            for (int mf = 0; mf < 4; mf++)
#pragma unroll
                for (int nf = 0; nf < 4; nf++)
                    acc[mf][nf] = __builtin_amdgcn_mfma_f32_16x16x32_bf16(
                        af[mf], bfr[nf], acc[mf][nf], 0, 0, 0);
        }
    }

    const float* bz = bias + z * sBb;
#pragma unroll
    for (int mf = 0; mf < 4; mf++) {
#pragma unroll
        for (int reg = 0; reg < 4; reg++) {
            int gr = row0 + wr + (mf << 4) + (lg << 2) + reg;
            if (gr >= M) continue;
#pragma unroll
            for (int nf = 0; nf < 4; nf++) {
                int gc = col0 + wc + (nf << 4) + l15;
                float v = acc[mf][nf][reg];
                if (addbias) v += bz[gc];
                v *= alpha;
                if (relu) v = fmaxf(v, 0.f);
                if (resmode == 1) {
                    v += res[z * sRb + (long long)gr * N + gc];
                } else if (resmode == 2) {
                    int n = gr >> 4, c = gr & 15;
                    int st, sd;
                    if (gc < 128) { st = n * STR_ + c; sd = gc; }
                    else {
                        int jj = gc - 128;
                        st = n * STR_ + (jj & 15);
                        sd = 128 + ((jj >> 4) << 4) + c;
                    }
                    v += xg[((long long)z * L_ + st) * D_ + sd];
                }
                long long co = z * sCb + (long long)gr * N + gc;
                if (outbf16) ((unsigned short*)Cout)[co] = f2bf(v);
                else         ((float*)Cout)[co] = v;
            }
        }
    }
}

// ---------------------------------------------------------------------------
// Clip attention (bf16 io, f32 math): block per (b,n,h). 16x16 scores.
// ---------------------------------------------------------------------------
__global__ __launch_bounds__(256) void k_clip_attn(const unsigned short* __restrict__ q,
                                                   const unsigned short* __restrict__ k,
                                                   const unsigned short* __restrict__ v,
                                                   unsigned short* __restrict__ ctx)
{
    __shared__ float qs[CS_][65], ks[CS_][65], vs[CS_][65], ps[CS_][17];
    int id = blockIdx.x;
    int h = id & (H_ - 1);
    int n = (id / H_) % NC_;
    int b = id / (H_ * NC_);
    long long base = (((long long)b * NC_ + n) * CS_) * D_ + h * HD_;
    int tid = threadIdx.x;
#pragma unroll
    for (int i = 0; i < 4; i++) {
        int e = tid + i * 256;
        int r = e >> 6, c = e & 63;
        qs[r][c] = bf2f(q[base + (long long)r * D_ + c]);
        ks[r][c] = bf2f(k[base + (long long)r * D_ + c]);
        vs[r][c] = bf2f(v[base + (long long)r * D_ + c]);
    }
    __syncthreads();
    int qr = tid >> 4, kc = tid & 15;
    float s = 0.f;
#pragma unroll
    for (int d = 0; d < HD_; d++) s += qs[qr][d] * ks[kc][d];
    float m = s;
#pragma unroll
    for (int off = 1; off < 16; off <<= 1) m = fmaxf(m, __shfl_xor(m, off));
    float e = __expf(s - m);
    float sum = e;
#pragma unroll
    for (int off = 1; off < 16; off <<= 1) sum += __shfl_xor(sum, off);
    ps[qr][kc] = e / sum;
    __syncthreads();
    int dg = (tid & 15) * 4;
    float o0 = 0, o1 = 0, o2 = 0, o3 = 0;
#pragma unroll
    for (int kk = 0; kk < CS_; kk++) {
        float pp = ps[qr][kk];
        o0 += pp * vs[kk][dg + 0];
        o1 += pp * vs[kk][dg + 1];
        o2 += pp * vs[kk][dg + 2];
        o3 += pp * vs[kk][dg + 3];
    }
    long long ob = base + (long long)qr * D_ + dg;
    ctx[ob + 0] = f2bf(o0);
    ctx[ob + 1] = f2bf(o1);
    ctx[ob + 2] = f2bf(o2);
    ctx[ob + 3] = f2bf(o3);
}

// ---------------------------------------------------------------------------
// Global flash attention via MFMA. Block = (b, h, 64-row q-tile), 4 waves.
// Each wave owns 16 q-rows. Online softmax in-register (C-layout:
// col=lane&15=token, row=(lane>>4)*4+reg=q-row). P->per-wave LDS (swizzled,
// no barrier), PV with V staged transposed. All LDS frag reads <=2-way.
// ---------------------------------------------------------------------------
__global__ __launch_bounds__(256) void k_flash_mfma(
    const unsigned short* __restrict__ q,
    const unsigned short* __restrict__ kk,
    const unsigned short* __restrict__ vv,
    unsigned short* __restrict__ out)
{
    __shared__ unsigned short lQ[4096], lK[4096], lV[4096], lP[4096];
    int id = blockIdx.x;
    int qt = id % NQT_;
    int h  = (id / NQT_) & (H_ - 1);
    int b  = id / (NQT_ * H_);
    int tid = threadIdx.x;
    int q0 = qt * 64;
    long long base = (long long)b * L_ * D_ + h * HD_;

    int srow = tid & 63;           // staging row / token
    int sd0  = (tid >> 6) << 4;    // 0,16,32,48
    int skey = srow & 7;
    int ss0  = sd0 >> 3;

    // ---- stage Q (64 x 64, swizzled) ----
    {
        int gr = q0 + srow;
        short8 a0 = (short8)0, a1 = (short8)0;
        if (gr < L_) {
            const unsigned short* p = q + base + (long long)gr * D_ + sd0;
            a0 = *(const short8*)p;
            a1 = *(const short8*)(p + 8);
        }
        *(short8*)(lQ + srow * 64 + (((ss0    ) ^ skey) << 3)) = a0;
        *(short8*)(lQ + srow * 64 + (((ss0 + 1) ^ skey) << 3)) = a1;
    }
    __syncthreads();

    int w = tid >> 6, lane = tid & 63;
    int l15 = lane & 15, lg = lane >> 4;
    int qrow = (w << 4) + l15;
    short8 qf[2];
#pragma unroll
    for (int ks = 0; ks < 2; ks++) {
        int slot = (ks << 2) + lg;
        qf[ks] = *(const short8*)(lQ + qrow * 64 + ((slot ^ (qrow & 7)) << 3));
    }
    unsigned short* lPw = lP + (w << 10);   // per-wave 16x64

    float m[4], l[4];
    f32x4 oacc[4];
#pragma unroll
    for (int r = 0; r < 4; r++) { m[r] = -1e30f; l[r] = 0.f; }
#pragma unroll
    for (int nf = 0; nf < 4; nf++) oacc[nf] = (f32x4)0.f;

    for (int kt = 0; kt < NQT_; kt++) {
        int k0 = kt * 64;
        __syncthreads();           // prev iter's lK/lV reads done
        {   // stage K (row-swizzled) and V (transposed, swizzled)
            int gr = k0 + srow;
            short8 a0 = (short8)0, a1 = (short8)0, v0 = (short8)0, v1 = (short8)0;
            if (gr < L_) {
                const unsigned short* pk = kk + base + (long long)gr * D_ + sd0;
                a0 = *(const short8*)pk;
                a1 = *(const short8*)(pk + 8);
                const unsigned short* pv = vv + base + (long long)gr * D_ + sd0;
                v0 = *(const short8*)pv;
                v1 = *(const short8*)(pv + 8);
            }
            *(short8*)(lK + srow * 64 + (((ss0    ) ^ skey) << 3)) = a0;
            *(short8*)(lK + srow * 64 + (((ss0 + 1) ^ skey) << 3)) = a1;
            int ts = srow >> 3, t7 = srow & 7;
#pragma unroll
            for (int i = 0; i < 8; i++) {
                int d = sd0 + i;
                lV[d * 64 + ((ts ^ (d & 7)) << 3) + t7] = (unsigned short)v0[i];
            }
#pragma unroll
            for (int i = 0; i < 8; i++) {
                int d = sd0 + 8 + i;
                lV[d * 64 + ((ts ^ (d & 7)) << 3) + t7] = (unsigned short)v1[i];
            }
        }
        __syncthreads();

        // ---- QK^T ----
        f32x4 acc[4];
#pragma unroll
        for (int nf = 0; nf < 4; nf++) {
            acc[nf] = (f32x4)0.f;
            int tok = (nf << 4) + l15;
            int key = tok & 7;
#pragma unroll
            for (int ks = 0; ks < 2; ks++) {
                int slot = (ks << 2) + lg;
                short8 kf = *(const short8*)(lK + tok * 64 + ((slot ^ key) << 3));
                acc[nf] = __builtin_amdgcn_mfma_f32_16x16x32_bf16(qf[ks], kf, acc[nf], 0, 0, 0);
            }
        }
        // ---- mask + row max ----
        float rm[4];
#pragma unroll
        for (int r = 0; r < 4; r++) rm[r] = -1e30f;
#pragma unroll
        for (int nf = 0; nf < 4; nf++) {
            bool oob = (k0 + (nf << 4) + l15) >= L_;
#pragma unroll
            for (int r = 0; r < 4; r++) {
                if (oob) acc[nf][r] = -1e30f;
                rm[r] = fmaxf(rm[r], acc[nf][r]);
            }
        }
#pragma unroll
        for (int off = 1; off < 16; off <<= 1) {
#pragma unroll
            for (int r = 0; r < 4; r++) rm[r] = fmaxf(rm[r], __shfl_xor(rm[r], off));
        }
        float sc[4], ls[4];
#pragma unroll
        for (int r = 0; r < 4; r++) {
            float mn = fmaxf(m[r], rm[r]);
            sc[r] = __expf(m[r] - mn);
            m[r] = mn;
            ls[r] = 0.f;
        }
        // ---- P = exp(S-m) -> per-wave LDS (bf16) ----
#pragma unroll
        for (int nf = 0; nf < 4; nf++) {
            int tok = (nf << 4) + l15;
            int slot = tok >> 3, t7 = tok & 7;
#pragma unroll
            for (int r = 0; r < 4; r++) {
                float p = __expf(acc[nf][r] - m[r]);
                ls[r] += p;
                int row = (lg << 2) + r;
                lPw[row * 64 + ((slot ^ (row & 7)) << 3) + t7] = f2bf(p);
            }
        }
#pragma unroll
        for (int off = 1; off < 16; off <<= 1) {
#pragma unroll
            for (int r = 0; r < 4; r++) ls[r] += __shfl_xor(ls[r], off);
        }
#pragma unroll
        for (int r = 0; r < 4; r++) l[r] = l[r] * sc[r] + ls[r];
#pragma unroll
        for (int nf = 0; nf < 4; nf++) {
#pragma unroll
            for (int r = 0; r < 4; r++) oacc[nf][r] *= sc[r];
        }
        // ---- PV (wave-private lP: in-order DS, no barrier needed) ----
#pragma unroll
        for (int ks = 0; ks < 2; ks++) {
            int slot = (ks << 2) + lg;
            short8 pa = *(const short8*)(lPw + l15 * 64 + ((slot ^ (l15 & 7)) << 3));
#pragma unroll
            for (int nf = 0; nf < 4; nf++) {
                int d = (nf << 4) + l15;
                short8 vb = *(const short8*)(lV + d * 64 + ((slot ^ (d & 7)) << 3));
                oacc[nf] = __builtin_amdgcn_mfma_f32_16x16x32_bf16(pa, vb, oacc[nf], 0, 0, 0);
            }
        }
    }
    // ---- store O / l ----
#pragma unroll
    for (int r = 0; r < 4; r++) {
        int gr = q0 + (w << 4) + (lg << 2) + r;
        if (gr >= L_) continue;
        float inv = 1.f / l[r];
        long long ob = base + (long long)gr * D_;
#pragma unroll
        for (int nf = 0; nf < 4; nf++)
            out[ob + (nf << 4) + l15] = f2bf(oacc[nf][r] * inv);
    }
}

// ---------------------------------------------------------------------------
static inline void gemm(hipStream_t st, const unsigned short* A, const unsigned short* WTp,
                        const float* bias, const float* res, const float* xg, void* C,
                        int M, int N, int K, int G,
                        long long sAb, long long sWb, long long sBb,
                        long long sRb, long long sCb,
                        float alpha, int relu, int addbias, int resmode, int outbf16)
{
    dim3 grid(N / 128, (M + 127) / 128, G);
    k_gemm_mfma<<<grid, 256, 0, st>>>(A, WTp, bias, res, xg, C, M, N, K,
                                      sAb, sWb, sBb, sRb, sCb,
                                      alpha, relu, addbias, resmode, outbf16);
}
static inline void wt(hipStream_t st, const float* W, unsigned short* T,
                      int rowStride, long long sWb, long long sTb, int G)
{
    k_wt<<<dim3(16, 16, G), 256, 0, st>>>(W, T, rowStride, sWb, sTb);
}

extern "C" void kernel_launch(void* const* d_in, const int* in_sizes, int n_in,
                              void* d_out, int out_size, void* d_ws, size_t ws_size,
                              hipStream_t stream)
{
    (void)in_sizes; (void)n_in; (void)out_size; (void)ws_size;
    const float* x      = (const float*)d_in[0];
    const float* g_ln_g = (const float*)d_in[2];
    const float* g_ln_b = (const float*)d_in[3];
    const float* Wq = (const float*)d_in[4];
    const float* Wk = (const float*)d_in[5];
    const float* Wv = (const float*)d_in[6];
    const float* Wo = (const float*)d_in[7];
    const float* bq = (const float*)d_in[8];
    const float* bk = (const float*)d_in[9];
    const float* bv = (const float*)d_in[10];
    const float* bo = (const float*)d_in[11];
    const float* f_ln_g = (const float*)d_in[12];
    const float* f_ln_b = (const float*)d_in[13];
    const float* W1 = (const float*)d_in[14];
    const float* b1 = (const float*)d_in[15];
    const float* W2 = (const float*)d_in[16];
    const float* b2 = (const float*)d_in[17];
    const float* c_ln_g = (const float*)d_in[18];
    const float* c_ln_b = (const float*)d_in[19];
    const float* cWq = (const float*)d_in[20];
    const float* cWk = (const float*)d_in[21];
    const float* cWv = (const float*)d_in[22];
    const float* cWo = (const float*)d_in[23];
    const float* cbq = (const float*)d_in[24];
    const float* cbk = (const float*)d_in[25];
    const float* cbv = (const float*)d_in[26];
    const float* cbo = (const float*)d_in[27];
    const float* cf_ln_g = (const float*)d_in[28];
    const float* cf_ln_b = (const float*)d_in[29];
    const float* cW1 = (const float*)d_in[30];
    const float* cb1 = (const float*)d_in[31];
    const float* cW2 = (const float*)d_in[32];
    const float* cb2 = (const float*)d_in[33];

    // workspace layout (bytes): 209 MB total
    char* wsb = (char*)d_ws;
    float*          bA = (float*)wsb;                               // 64MB f32: clips -> hcl -> h
    unsigned short* bB = (unsigned short*)(wsb + (64ll  << 20));    // 32MB bf16: LN outs / ctx
    unsigned short* bQ = (unsigned short*)(wsb + (96ll  << 20));    // 32MB bf16
    unsigned short* bK = (unsigned short*)(wsb + (128ll << 20));    // 32MB bf16
    unsigned short* bV = (unsigned short*)(wsb + (160ll << 20));    // 32MB bf16 (also fmid chunks)
    unsigned short* wT = (unsigned short*)(wsb + (192ll << 20));    // 17MB bf16 W^T scratch
    float*          CO = (float*)(wsb + (96ll << 20));              // clips_out f32 (overlays bQ+bK)

    const long long SZC = (long long)B_ * MC_ * D_;
    const long long sA  = (long long)MC_ * D_;       // per-batch A stride (clip)
    const long long sWW = (long long)D_ * D_;        // 512*512 (WT batch stride)
    const int MG = B_ * L_;

    // ================= clip path =================
    k_build_clips<<<(int)(SZC / 256), 256, 0, stream>>>(x, bA);
    k_ln<<<B_ * MC_, 256, 0, stream>>>(bA, bB, c_ln_g, c_ln_b, MC_, D_, 0);
    wt(stream, cWq, wT, D_, sWW, sWW, B_);
    gemm(stream, bB, wT, cbq, nullptr, nullptr, bQ, MC_, D_, D_, B_,
         sA, sWW, D_, 0, sA, 0.125f, 0, 1, 0, 1);
    wt(stream, cWk, wT, D_, sWW, sWW, B_);
    gemm(stream, bB, wT, cbk, nullptr, nullptr, bK, MC_, D_, D_, B_,
         sA, sWW, D_, 0, sA, 1.0f, 0, 1, 0, 1);
    wt(stream, cWv, wT, D_, sWW, sWW, B_);
    gemm(stream, bB, wT, cbv, nullptr, nullptr, bV, MC_, D_, D_, B_,
         sA, sWW, D_, 0, sA, 1.0f, 0, 1, 0, 1);
    k_clip_attn<<<B_ * NC_ * H_, 256, 0, stream>>>(bQ, bK, bV, bB);      // ctx -> bB
    wt(stream, cWo, wT, D_, sWW, sWW, B_);
    gemm(stream, bB, wT, cbo, nullptr, x, bA, MC_, D_, D_, B_,
         sA, sWW, D_, 0, sA, 1.0f, 0, 1, 2, 0);                          // hcl f32 -> bA
    k_ln<<<B_ * MC_, 256, 0, stream>>>(bA, bB, cf_ln_g, cf_ln_b, MC_, D_, 0);
    for (int c = 0; c < 4; c++) {   // FFN chunked over FF (4 x 512)
        wt(stream, cW1 + c * 512, wT, FF_, (long long)D_ * FF_, sWW, B_);
        gemm(stream, bB, wT, cb1 + c * 512, nullptr, nullptr, bV, MC_, 512, D_, B_,
             sA, sWW, FF_, 0, sA, 1.0f, 1, 1, 0, 1);                     // fmid chunk (relu)
        wt(stream, cW2 + (long long)c * 512 * D_, wT, D_, (long long)FF_ * D_, sWW, B_);
        gemm(stream, bV, wT, cb2, (c == 0) ? bA : CO, nullptr, CO, MC_, D_, 512, B_,
             sA, sWW, D_, sA, sA, 1.0f, 0, (c == 0) ? 1 : 0, 1, 0);      // clips_out f32
    }

    // ================= global path =================
    k_ln<<<MG, 256, 0, stream>>>(CO, bB, g_ln_g, g_ln_b, L_, 0, 1);      // xn (gathered)
    wt(stream, Wq, wT, D_, 0, 0, 1);
    gemm(stream, bB, wT, bq, nullptr, nullptr, bQ, MG, D_, D_, 1,
         0, 0, 0, 0, 0, 0.125f, 0, 1, 0, 1);
    wt(stream, Wk, wT, D_, 0, 0, 1);
    gemm(stream, bB, wT, bk, nullptr, nullptr, bK, MG, D_, D_, 1,
         0, 0, 0, 0, 0, 1.0f, 0, 1, 0, 1);
    wt(stream, Wv, wT, D_, 0, 0, 1);
    gemm(stream, bB, wT, bv, nullptr, nullptr, bV, MG, D_, D_, 1,
         0, 0, 0, 0, 0, 1.0f, 0, 1, 0, 1);
    k_flash_mfma<<<B_ * H_ * NQT_, 256, 0, stream>>>(bQ, bK, bV, bB);    // ctx2 -> bB
    wt(stream, Wo, wT, D_, 0, 0, 1);
    gemm(stream, bB, wT, bo, x, nullptr, bA, MG, D_, D_, 1,
         0, 0, 0, 0, 0, 1.0f, 0, 1, 1, 0);                               // h f32 -> bA
    k_ln<<<MG, 256, 0, stream>>>(bA, bB, f_ln_g, f_ln_b, MG, 0, 0);      // hn
    for (int c = 0; c < 4; c++) {
        wt(stream, W1 + c * 512, wT, FF_, 0, 0, 1);
        gemm(stream, bB, wT, b1 + c * 512, nullptr, nullptr, bV, MG, 512, D_, 1,
             0, 0, 0, 0, 0, 1.0f, 1, 1, 0, 1);                           // mid2 chunk
        wt(stream, W2 + (long long)c * 512 * D_, wT, D_, 0, 0, 1);
        gemm(stream, bV, wT, b2, (c == 0) ? bA : (float*)d_out, nullptr, d_out,
             MG, D_, 512, 1, 0, 0, 0, 0, 0, 1.0f, 0, (c == 0) ? 1 : 0, 1, 0);
    }
}

// Round 5
// 2159.717 us; speedup vs baseline: 4.3829x; 1.2096x over previous
//
#include <hip/hip_runtime.h>

#define B_   32
#define L_   796
#define D_   512
#define H_   8
#define HD_  64
#define FF_  2048
#define CS_  16
#define STR_ 13
#define NC_  61
#define NQT_ 13
#define MC_  976   // NC_*CS_ rows per batch (clip path)

typedef __attribute__((ext_vector_type(8))) short short8;
typedef __attribute__((ext_vector_type(4))) float f32x4;

__device__ __forceinline__ unsigned short f2bf(float x) {
    unsigned u = __float_as_uint(x);
    unsigned r = u + 0x7FFFu + ((u >> 16) & 1u);   // RNE
    return (unsigned short)(r >> 16);
}
__device__ __forceinline__ float bf2f(unsigned short h) {
    return __uint_as_float(((unsigned)h) << 16);
}
// async global->LDS, 16B per lane. LDS dest = wave-uniform base + lane*16.
__device__ __forceinline__ void gload16(const unsigned short* g, unsigned short* l) {
    __builtin_amdgcn_global_load_lds(
        (const __attribute__((address_space(1))) void*)g,
        (__attribute__((address_space(3))) void*)l, 16, 0, 0);
}

// ---------------------------------------------------------------------------
// build clips (f32): gather windows + channel shuffle
// ---------------------------------------------------------------------------
__global__ __launch_bounds__(256) void k_build_clips(const float* __restrict__ x,
                                                     float* __restrict__ clips)
{
    long long idx = (long long)blockIdx.x * 256 + threadIdx.x;   // B*NC*CS*D
    int d = idx & 511;
    long long t = idx >> 9;
    int c = t & 15;
    long long nn = t >> 4;
    int n = (int)(nn % NC_);
    int b = (int)(nn / NC_);
    int src_t, src_d;
    if (d < 128) { src_t = n * STR_ + c; src_d = d; }
    else {
        int j = d - 128;
        src_t = n * STR_ + (j & 15);
        src_d = 128 + (j >> 4) * 16 + c;
    }
    clips[idx] = x[((long long)b * L_ + src_t) * D_ + src_d];
}

// ---------------------------------------------------------------------------
// LayerNorm D=512, f32 in -> bf16 out. gather=1: clip-reconstruction row remap.
// ---------------------------------------------------------------------------
__global__ __launch_bounds__(256) void k_ln(const float* __restrict__ in,
                                            unsigned short* __restrict__ out,
                                            const float* __restrict__ gamma,
                                            const float* __restrict__ beta,
                                            int rows_per_batch, int gstride, int gather)
{
    __shared__ float red[8];
    long long row = blockIdx.x;
    long long srow = row;
    int b;
    if (gather) {
        int p = (int)(row % L_);
        b = (int)(row / L_);
        int ci = p / STR_; if (ci > NC_ - 1) ci = NC_ - 1;
        int off = p - ci * STR_;
        srow = ((long long)b * NC_ + ci) * CS_ + off;
    } else {
        b = (int)(row / rows_per_batch);
    }
    const float* xr = in + srow * D_;
    int tid = threadIdx.x;
    float v0 = xr[tid], v1 = xr[tid + 256];
    float s = v0 + v1;
#pragma unroll
    for (int off = 1; off < 64; off <<= 1) s += __shfl_xor(s, off);
    if ((tid & 63) == 0) red[tid >> 6] = s;
    __syncthreads();
    float mean = (red[0] + red[1] + red[2] + red[3]) * (1.0f / 512.0f);
    float d0 = v0 - mean, d1 = v1 - mean;
    float vv = d0 * d0 + d1 * d1;
#pragma unroll
    for (int off = 1; off < 64; off <<= 1) vv += __shfl_xor(vv, off);
    if ((tid & 63) == 0) red[4 + (tid >> 6)] = vv;
    __syncthreads();
    float var = (red[4] + red[5] + red[6] + red[7]) * (1.0f / 512.0f);
    float rstd = rsqrtf(var + 1e-6f);
    const float* g  = gamma + (long long)b * gstride;
    const float* bt = beta  + (long long)b * gstride;
    unsigned short* o = out + row * D_;
    o[tid]       = f2bf(d0 * rstd * g[tid]       + bt[tid]);
    o[tid + 256] = f2bf(d1 * rstd * g[tid + 256] + bt[tid + 256]);
}

// ---------------------------------------------------------------------------
// Weight transpose+convert: W (f32, [K rows x N cols], row stride rowStride)
// -> T (bf16, [N][K], row stride tStride). grid (N/32, K/32, G).
// ---------------------------------------------------------------------------
__global__ __launch_bounds__(256) void k_wt(const float* __restrict__ W,
                                            unsigned short* __restrict__ T,
                                            int rowStride, int tStride,
                                            long long sWb, long long sTb)
{
    __shared__ float t[32][33];
    int z = blockIdx.z;
    const float* Wz = W + (long long)z * sWb;
    unsigned short* Tz = T + (long long)z * sTb;
    int n0 = blockIdx.x << 5, k0 = blockIdx.y << 5;
    int tx = threadIdx.x & 31, ty = threadIdx.x >> 5;
#pragma unroll
    for (int i = 0; i < 4; i++) {
        int k = ty + (i << 3);
        t[k][tx] = Wz[(long long)(k0 + k) * rowStride + n0 + tx];
    }
    __syncthreads();
#pragma unroll
    for (int i = 0; i < 4; i++) {
        int n = ty + (i << 3);
        Tz[(long long)(n0 + n) * tStride + k0 + tx] = f2bf(t[tx][n]);
    }
}

// 4 square 512x512 weights in one launch (z selects tensor). T + z*262144.
__global__ __launch_bounds__(256) void k_wt4(const float* __restrict__ Wa,
                                             const float* __restrict__ Wb,
                                             const float* __restrict__ Wc,
                                             const float* __restrict__ Wd,
                                             unsigned short* __restrict__ T)
{
    __shared__ float t[32][33];
    int z = blockIdx.z;
    const float* Wz = (z == 0) ? Wa : (z == 1) ? Wb : (z == 2) ? Wc : Wd;
    unsigned short* Tz = T + (long long)z * 262144;
    int n0 = blockIdx.x << 5, k0 = blockIdx.y << 5;
    int tx = threadIdx.x & 31, ty = threadIdx.x >> 5;
#pragma unroll
    for (int i = 0; i < 4; i++) {
        int k = ty + (i << 3);
        t[k][tx] = Wz[(long long)(k0 + k) * 512 + n0 + tx];
    }
    __syncthreads();
#pragma unroll
    for (int i = 0; i < 4; i++) {
        int n = ty + (i << 3);
        Tz[(long long)(n0 + n) * 512 + k0 + tx] = f2bf(t[tx][n]);
    }
}

// ---------------------------------------------------------------------------
// bf16 MFMA GEMM with global_load_lds staging (m97 pattern, pre-swizzled src).
// A: [M][K] bf16 (k-contig). WT: [N][ldwk] bf16 (k-contig rows).
// 128x128 tile, BK=64, 4 waves x (64x64). LDS[row][slot] = G[row][slot^(row&7)].
// ---------------------------------------------------------------------------
__global__ __launch_bounds__(256) void k_gemm_mfma(
    const unsigned short* __restrict__ A, const unsigned short* __restrict__ WT,
    const float* __restrict__ bias, const float* __restrict__ res,
    const float* __restrict__ xg, void* __restrict__ Cout,
    int M, int N, int K, int ldwk,
    long long sAb, long long sWb, long long sBb, long long sRb, long long sCb,
    float alpha, int relu, int addbias, int resmode, int outbf16)
{
    __shared__ unsigned short lds[16384];      // 32 KB: A tile + W tile
    unsigned short* lA = lds;
    unsigned short* lW = lds + 8192;
    int tid = threadIdx.x;
    int z = blockIdx.z;
    int row0 = blockIdx.y << 7, col0 = blockIdx.x << 7;
    const unsigned short* Ab = A + z * sAb;
    const unsigned short* Wb = WT + z * sWb;

    int w = tid >> 6, lane = tid & 63;
    int wr = (w >> 1) << 6, wc = (w & 1) << 6;
    int l15 = lane & 15, lg = lane >> 4;
    int lrow = lane >> 3, lslot = lane & 7;

    f32x4 acc[4][4];
#pragma unroll
    for (int i = 0; i < 4; i++)
#pragma unroll
        for (int j = 0; j < 4; j++) acc[i][j] = (f32x4)0.f;

    for (int k0 = 0; k0 < K; k0 += 64) {
        __syncthreads();           // prior-iter LDS reads done
#pragma unroll
        for (int i = 0; i < 4; i++) {
            int cb = (w << 5) + (i << 3);          // chunk base row (8 rows/chunk)
            int rr = cb + lrow;
            gload16(Ab + (long long)(row0 + rr) * K + k0 + ((lslot ^ (rr & 7)) << 3),
                    lA + (cb << 6));
            gload16(Wb + (long long)(col0 + rr) * ldwk + k0 + ((lslot ^ (rr & 7)) << 3),
                    lW + (cb << 6));
        }
        __syncthreads();           // drains vmcnt -> tiles resident
#pragma unroll
        for (int ks = 0; ks < 2; ks++) {
            short8 af[4], bfr[4];
#pragma unroll
            for (int mf = 0; mf < 4; mf++) {
                int r = wr + (mf << 4) + l15;
                int slot = ((ks << 2) + lg) ^ (r & 7);
                af[mf] = *(const short8*)(lA + (r << 6) + (slot << 3));
            }
#pragma unroll
            for (int nf = 0; nf < 4; nf++) {
                int r = wc + (nf << 4) + l15;
                int slot = ((ks << 2) + lg) ^ (r & 7);
                bfr[nf] = *(const short8*)(lW + (r << 6) + (slot << 3));
            }
#pragma unroll
            for (int mf = 0; mf < 4; mf++)
#pragma unroll
                for (int nf = 0; nf < 4; nf++)
                    acc[mf][nf] = __builtin_amdgcn_mfma_f32_16x16x32_bf16(
                        af[mf], bfr[nf], acc[mf][nf], 0, 0, 0);
        }
    }

    const float* bz = bias + z * sBb;
#pragma unroll
    for (int mf = 0; mf < 4; mf++) {
#pragma unroll
        for (int reg = 0; reg < 4; reg++) {
            int gr = row0 + wr + (mf << 4) + (lg << 2) + reg;
            if (gr >= M) continue;
#pragma unroll
            for (int nf = 0; nf < 4; nf++) {
                int gc = col0 + wc + (nf << 4) + l15;
                float v = acc[mf][nf][reg];
                if (addbias) v += bz[gc];
                v *= alpha;
                if (relu) v = fmaxf(v, 0.f);
                if (resmode == 1) {
                    v += res[z * sRb + (long long)gr * N + gc];
                } else if (resmode == 2) {
                    int n = gr >> 4, c = gr & 15;
                    int st, sd;
                    if (gc < 128) { st = n * STR_ + c; sd = gc; }
                    else {
                        int jj = gc - 128;
                        st = n * STR_ + (jj & 15);
                        sd = 128 + ((jj >> 4) << 4) + c;
                    }
                    v += xg[((long long)z * L_ + st) * D_ + sd];
                }
                long long co = z * sCb + (long long)gr * N + gc;
                if (outbf16) ((unsigned short*)Cout)[co] = f2bf(v);
                else         ((float*)Cout)[co] = v;
            }
        }
    }
}

// ---------------------------------------------------------------------------
// Clip attention (bf16 io, f32 math): block per (b,n,h). 16x16 scores.
// ---------------------------------------------------------------------------
__global__ __launch_bounds__(256) void k_clip_attn(const unsigned short* __restrict__ q,
                                                   const unsigned short* __restrict__ k,
                                                   const unsigned short* __restrict__ v,
                                                   unsigned short* __restrict__ ctx)
{
    __shared__ float qs[CS_][65], ks[CS_][65], vs[CS_][65], ps[CS_][17];
    int id = blockIdx.x;
    int h = id & (H_ - 1);
    int n = (id / H_) % NC_;
    int b = id / (H_ * NC_);
    long long base = (((long long)b * NC_ + n) * CS_) * D_ + h * HD_;
    int tid = threadIdx.x;
#pragma unroll
    for (int i = 0; i < 4; i++) {
        int e = tid + i * 256;
        int r = e >> 6, c = e & 63;
        qs[r][c] = bf2f(q[base + (long long)r * D_ + c]);
        ks[r][c] = bf2f(k[base + (long long)r * D_ + c]);
        vs[r][c] = bf2f(v[base + (long long)r * D_ + c]);
    }
    __syncthreads();
    int qr = tid >> 4, kc = tid & 15;
    float s = 0.f;
#pragma unroll
    for (int d = 0; d < HD_; d++) s += qs[qr][d] * ks[kc][d];
    float m = s;
#pragma unroll
    for (int off = 1; off < 16; off <<= 1) m = fmaxf(m, __shfl_xor(m, off));
    float e = __expf(s - m);
    float sum = e;
#pragma unroll
    for (int off = 1; off < 16; off <<= 1) sum += __shfl_xor(sum, off);
    ps[qr][kc] = e / sum;
    __syncthreads();
    int dg = (tid & 15) * 4;
    float o0 = 0, o1 = 0, o2 = 0, o3 = 0;
#pragma unroll
    for (int kk = 0; kk < CS_; kk++) {
        float pp = ps[qr][kk];
        o0 += pp * vs[kk][dg + 0];
        o1 += pp * vs[kk][dg + 1];
        o2 += pp * vs[kk][dg + 2];
        o3 += pp * vs[kk][dg + 3];
    }
    long long ob = base + (long long)qr * D_ + dg;
    ctx[ob + 0] = f2bf(o0);
    ctx[ob + 1] = f2bf(o1);
    ctx[ob + 2] = f2bf(o2);
    ctx[ob + 3] = f2bf(o3);
}

// ---------------------------------------------------------------------------
// Global flash attention via MFMA, gload_lds Q/K staging.
// Block = (b, h, 64-row q-tile), 4 waves x 16 q-rows.
// ---------------------------------------------------------------------------
__global__ __launch_bounds__(256) void k_flash_mfma(
    const unsigned short* __restrict__ q,
    const unsigned short* __restrict__ kk,
    const unsigned short* __restrict__ vv,
    unsigned short* __restrict__ out)
{
    __shared__ unsigned short lQ[4096], lK[4096], lV[4096], lP[4096];
    int id = blockIdx.x;
    int qt = id % NQT_;
    int h  = (id / NQT_) & (H_ - 1);
    int b  = id / (NQT_ * H_);
    int tid = threadIdx.x;
    int q0 = qt * 64;
    long long base = (long long)b * L_ * D_ + h * HD_;

    int w = tid >> 6, lane = tid & 63;
    int l15 = lane & 15, lg = lane >> 4;
    int lrow = lane >> 3, lslot = lane & 7;
    int srow = lane;               // V staging: token
    int sd0  = w << 4;             // V staging: d-group 0,16,32,48

    // ---- stage Q via gload_lds (64 x 64, src pre-swizzled) ----
#pragma unroll
    for (int i = 0; i < 2; i++) {
        int cb = (w << 4) + (i << 3);
        int rr = cb + lrow;
        gload16(q + base + (long long)(q0 + rr) * D_ + ((lslot ^ (rr & 7)) << 3),
                lQ + (cb << 6));
    }
    __syncthreads();

    int qrow = (w << 4) + l15;
    short8 qf[2];
#pragma unroll
    for (int ks = 0; ks < 2; ks++) {
        int slot = (ks << 2) + lg;
        qf[ks] = *(const short8*)(lQ + qrow * 64 + ((slot ^ (qrow & 7)) << 3));
    }
    unsigned short* lPw = lP + (w << 10);   // per-wave 16x64

    float m[4], l[4];
    f32x4 oacc[4];
#pragma unroll
    for (int r = 0; r < 4; r++) { m[r] = -1e30f; l[r] = 0.f; }
#pragma unroll
    for (int nf = 0; nf < 4; nf++) oacc[nf] = (f32x4)0.f;

    for (int kt = 0; kt < NQT_; kt++) {
        int k0 = kt * 64;
        __syncthreads();           // prev iter's lK/lV reads done
#pragma unroll
        for (int i = 0; i < 2; i++) {      // K via gload_lds
            int cb = (w << 4) + (i << 3);
            int rr = cb + lrow;
            gload16(kk + base + (long long)(k0 + rr) * D_ + ((lslot ^ (rr & 7)) << 3),
                    lK + (cb << 6));
        }
        {   // V: reg-stage transposed + swizzled (per-lane scatter)
            int gr = k0 + srow;
            short8 v0 = (short8)0, v1 = (short8)0;
            if (gr < L_) {
                const unsigned short* pv = vv + base + (long long)gr * D_ + sd0;
                v0 = *(const short8*)pv;
                v1 = *(const short8*)(pv + 8);
            }
            int ts = srow >> 3, t7 = srow & 7;
#pragma unroll
            for (int i = 0; i < 8; i++) {
                int d = sd0 + i;
                lV[d * 64 + ((ts ^ (d & 7)) << 3) + t7] = (unsigned short)v0[i];
            }
#pragma unroll
            for (int i = 0; i < 8; i++) {
                int d = sd0 + 8 + i;
                lV[d * 64 + ((ts ^ (d & 7)) << 3) + t7] = (unsigned short)v1[i];
            }
        }
        __syncthreads();

        // ---- QK^T ----
        f32x4 acc[4];
#pragma unroll
        for (int nf = 0; nf < 4; nf++) {
            acc[nf] = (f32x4)0.f;
            int tok = (nf << 4) + l15;
            int key = tok & 7;
#pragma unroll
            for (int ks = 0; ks < 2; ks++) {
                int slot = (ks << 2) + lg;
                short8 kf = *(const short8*)(lK + tok * 64 + ((slot ^ key) << 3));
                acc[nf] = __builtin_amdgcn_mfma_f32_16x16x32_bf16(qf[ks], kf, acc[nf], 0, 0, 0);
            }
        }
        // ---- mask + row max ----
        float rm[4];
#pragma unroll
        for (int r = 0; r < 4; r++) rm[r] = -1e30f;
#pragma unroll
        for (int nf = 0; nf < 4; nf++) {
            bool oob = (k0 + (nf << 4) + l15) >= L_;
#pragma unroll
            for (int r = 0; r < 4; r++) {
                if (oob) acc[nf][r] = -1e30f;
                rm[r] = fmaxf(rm[r], acc[nf][r]);
            }
        }
#pragma unroll
        for (int off = 1; off < 16; off <<= 1) {
#pragma unroll
            for (int r = 0; r < 4; r++) rm[r] = fmaxf(rm[r], __shfl_xor(rm[r], off));
        }
        float sc[4], ls[4];
#pragma unroll
        for (int r = 0; r < 4; r++) {
            float mn = fmaxf(m[r], rm[r]);
            sc[r] = __expf(m[r] - mn);
            m[r] = mn;
            ls[r] = 0.f;
        }
        // ---- P = exp(S-m) -> per-wave LDS (bf16) ----
#pragma unroll
        for (int nf = 0; nf < 4; nf++) {
            int tok = (nf << 4) + l15;
            int slot = tok >> 3, t7 = tok & 7;
#pragma unroll
            for (int r = 0; r < 4; r++) {
                float p = __expf(acc[nf][r] - m[r]);
                ls[r] += p;
                int row = (lg << 2) + r;
                lPw[row * 64 + ((slot ^ (row & 7)) << 3) + t7] = f2bf(p);
            }
        }
#pragma unroll
        for (int off = 1; off < 16; off <<= 1) {
#pragma unroll
            for (int r = 0; r < 4; r++) ls[r] += __shfl_xor(ls[r], off);
        }
#pragma unroll
        for (int r = 0; r < 4; r++) l[r] = l[r] * sc[r] + ls[r];
#pragma unroll
        for (int nf = 0; nf < 4; nf++) {
#pragma unroll
            for (int r = 0; r < 4; r++) oacc[nf][r] *= sc[r];
        }
        // ---- PV (wave-private lP: in-order DS, no barrier needed) ----
#pragma unroll
        for (int ks = 0; ks < 2; ks++) {
            int slot = (ks << 2) + lg;
            short8 pa = *(const short8*)(lPw + l15 * 64 + ((slot ^ (l15 & 7)) << 3));
#pragma unroll
            for (int nf = 0; nf < 4; nf++) {
                int d = (nf << 4) + l15;
                short8 vb = *(const short8*)(lV + d * 64 + ((slot ^ (d & 7)) << 3));
                oacc[nf] = __builtin_amdgcn_mfma_f32_16x16x32_bf16(pa, vb, oacc[nf], 0, 0, 0);
            }
        }
    }
    // ---- store ----
#pragma unroll
    for (int r = 0; r < 4; r++) {
        int gr = q0 + (w << 4) + (lg << 2) + r;
        if (gr >= L_) continue;
        float inv = 1.f / l[r];
        long long ob = base + (long long)gr * D_;
#pragma unroll
        for (int nf = 0; nf < 4; nf++)
            out[ob + (nf << 4) + l15] = f2bf(oacc[nf][r] * inv);
    }
}

// ---------------------------------------------------------------------------
static inline void gemm(hipStream_t st, const unsigned short* A, const unsigned short* WTp,
                        const float* bias, const float* res, const float* xg, void* C,
                        int M, int N, int K, int ldwk, int G,
                        long long sAb, long long sWb, long long sBb,
                        long long sRb, long long sCb,
                        float alpha, int relu, int addbias, int resmode, int outbf16)
{
    dim3 grid(N / 128, (M + 127) / 128, G);
    k_gemm_mfma<<<grid, 256, 0, st>>>(A, WTp, bias, res, xg, C, M, N, K, ldwk,
                                      sAb, sWb, sBb, sRb, sCb,
                                      alpha, relu, addbias, resmode, outbf16);
}

extern "C" void kernel_launch(void* const* d_in, const int* in_sizes, int n_in,
                              void* d_out, int out_size, void* d_ws, size_t ws_size,
                              hipStream_t stream)
{
    (void)in_sizes; (void)n_in; (void)out_size; (void)ws_size;
    const float* x      = (const float*)d_in[0];
    const float* g_ln_g = (const float*)d_in[2];
    const float* g_ln_b = (const float*)d_in[3];
    const float* Wq = (const float*)d_in[4];
    const float* Wk = (const float*)d_in[5];
    const float* Wv = (const float*)d_in[6];
    const float* Wo = (const float*)d_in[7];
    const float* bq = (const float*)d_in[8];
    const float* bk = (const float*)d_in[9];
    const float* bv = (const float*)d_in[10];
    const float* bo = (const float*)d_in[11];
    const float* f_ln_g = (const float*)d_in[12];
    const float* f_ln_b = (const float*)d_in[13];
    const float* W1 = (const float*)d_in[14];
    const float* b1 = (const float*)d_in[15];
    const float* W2 = (const float*)d_in[16];
    const float* b2 = (const float*)d_in[17];
    const float* c_ln_g = (const float*)d_in[18];
    const float* c_ln_b = (const float*)d_in[19];
    const float* cWq = (const float*)d_in[20];
    const float* cWk = (const float*)d_in[21];
    const float* cWv = (const float*)d_in[22];
    const float* cWo = (const float*)d_in[23];
    const float* cbq = (const float*)d_in[24];
    const float* cbk = (const float*)d_in[25];
    const float* cbv = (const float*)d_in[26];
    const float* cbo = (const float*)d_in[27];
    const float* cf_ln_g = (const float*)d_in[28];
    const float* cf_ln_b = (const float*)d_in[29];
    const float* cW1 = (const float*)d_in[30];
    const float* cb1 = (const float*)d_in[31];
    const float* cW2 = (const float*)d_in[32];
    const float* cb2 = (const float*)d_in[33];

    // workspace layout (bytes): 209 MB total
    char* wsb = (char*)d_ws;
    float*          bA = (float*)wsb;                               // 64MB f32: clips -> hcl -> h
    unsigned short* bB = (unsigned short*)(wsb + (64ll  << 20));    // 32MB bf16: LN outs / ctx
    unsigned short* bQ = (unsigned short*)(wsb + (96ll  << 20));    // 32MB bf16
    unsigned short* bK = (unsigned short*)(wsb + (128ll << 20));    // 32MB bf16
    unsigned short* bV = (unsigned short*)(wsb + (160ll << 20));    // 32MB bf16 (also clip fmid chunks)
    unsigned short* wT = (unsigned short*)(wsb + (192ll << 20));    // 17MB bf16 W^T scratch
    float*          CO = (float*)(wsb + (96ll << 20));              // clips_out f32 (overlays bQ+bK)
    unsigned short* fmidG = (unsigned short*)(wsb + (96ll << 20));  // global fmid chunk (52MB, overlays bQ+bK)

    const long long SZC = (long long)B_ * MC_ * D_;
    const long long sA  = (long long)MC_ * D_;       // per-batch A stride (clip)
    const long long sWW = (long long)D_ * D_;        // 512*512 (WT batch stride)
    const int MG = B_ * L_;

    // ================= clip path =================
    k_build_clips<<<(int)(SZC / 256), 256, 0, stream>>>(x, bA);
    k_ln<<<B_ * MC_, 256, 0, stream>>>(bA, bB, c_ln_g, c_ln_b, MC_, D_, 0);
    k_wt<<<dim3(16, 16, B_), 256, 0, stream>>>(cWq, wT, D_, D_, sWW, sWW);
    gemm(stream, bB, wT, cbq, nullptr, nullptr, bQ, MC_, D_, D_, D_, B_,
         sA, sWW, D_, 0, sA, 0.125f, 0, 1, 0, 1);
    k_wt<<<dim3(16, 16, B_), 256, 0, stream>>>(cWk, wT, D_, D_, sWW, sWW);
    gemm(stream, bB, wT, cbk, nullptr, nullptr, bK, MC_, D_, D_, D_, B_,
         sA, sWW, D_, 0, sA, 1.0f, 0, 1, 0, 1);
    k_wt<<<dim3(16, 16, B_), 256, 0, stream>>>(cWv, wT, D_, D_, sWW, sWW);
    gemm(stream, bB, wT, cbv, nullptr, nullptr, bV, MC_, D_, D_, D_, B_,
         sA, sWW, D_, 0, sA, 1.0f, 0, 1, 0, 1);
    k_clip_attn<<<B_ * NC_ * H_, 256, 0, stream>>>(bQ, bK, bV, bB);      // ctx -> bB
    k_wt<<<dim3(16, 16, B_), 256, 0, stream>>>(cWo, wT, D_, D_, sWW, sWW);
    gemm(stream, bB, wT, cbo, nullptr, x, bA, MC_, D_, D_, D_, B_,
         sA, sWW, D_, 0, sA, 1.0f, 0, 1, 2, 0);                          // hcl f32 -> bA
    k_ln<<<B_ * MC_, 256, 0, stream>>>(bA, bB, cf_ln_g, cf_ln_b, MC_, D_, 0);
    for (int c = 0; c < 4; c++) {   // clip FFN chunked over FF (4 x 512)
        k_wt<<<dim3(16, 16, B_), 256, 0, stream>>>(cW1 + c * 512, wT, FF_, D_,
                                                   (long long)D_ * FF_, sWW);
        gemm(stream, bB, wT, cb1 + c * 512, nullptr, nullptr, bV, MC_, 512, D_, D_, B_,
             sA, sWW, FF_, 0, sA, 1.0f, 1, 1, 0, 1);                     // fmid chunk (relu)
        k_wt<<<dim3(16, 16, B_), 256, 0, stream>>>(cW2 + (long long)c * 512 * D_, wT, D_, D_,
                                                   (long long)FF_ * D_, sWW);
        gemm(stream, bV, wT, cb2, (c == 0) ? bA : CO, nullptr, CO, MC_, D_, 512, D_, B_,
             sA, sWW, D_, sA, sA, 1.0f, 0, (c == 0) ? 1 : 0, 1, 0);      // clips_out f32
    }

    // ================= global path =================
    // pre-convert all global weights into wT (6.3 MB)
    unsigned short* gQw = wT;
    unsigned short* gKw = wT + 262144;
    unsigned short* gVw = wT + 2 * 262144;
    unsigned short* gOw = wT + 3 * 262144;
    unsigned short* gW1 = wT + 4 * 262144;   // [2048][512]
    unsigned short* gW2 = wT + 8 * 262144;   // [512][2048]
    k_wt4<<<dim3(16, 16, 4), 256, 0, stream>>>(Wq, Wk, Wv, Wo, wT);
    k_wt<<<dim3(64, 16, 1), 256, 0, stream>>>(W1, gW1, FF_, D_, 0, 0);
    k_wt<<<dim3(16, 64, 1), 256, 0, stream>>>(W2, gW2, D_, FF_, 0, 0);

    k_ln<<<MG, 256, 0, stream>>>(CO, bB, g_ln_g, g_ln_b, L_, 0, 1);      // xn (gathered)
    gemm(stream, bB, gQw, bq, nullptr, nullptr, bQ, MG, D_, D_, D_, 1,
         0, 0, 0, 0, 0, 0.125f, 0, 1, 0, 1);
    gemm(stream, bB, gKw, bk, nullptr, nullptr, bK, MG, D_, D_, D_, 1,
         0, 0, 0, 0, 0, 1.0f, 0, 1, 0, 1);
    gemm(stream, bB, gVw, bv, nullptr, nullptr, bV, MG, D_, D_, D_, 1,
         0, 0, 0, 0, 0, 1.0f, 0, 1, 0, 1);
    k_flash_mfma<<<B_ * H_ * NQT_, 256, 0, stream>>>(bQ, bK, bV, bB);    // ctx2 -> bB
    gemm(stream, bB, gOw, bo, x, nullptr, bA, MG, D_, D_, D_, 1,
         0, 0, 0, 0, 0, 1.0f, 0, 1, 1, 0);                               // h f32 -> bA
    k_ln<<<MG, 256, 0, stream>>>(bA, bB, f_ln_g, f_ln_b, MG, 0, 0);      // hn
    for (int c = 0; c < 2; c++) {    // global FFN chunked 2 x 1024 (no wt needed)
        gemm(stream, bB, gW1 + (long long)c * 1024 * 512, b1 + c * 1024,
             nullptr, nullptr, fmidG, MG, 1024, D_, D_, 1,
             0, 0, 0, 0, 0, 1.0f, 1, 1, 0, 1);                           // mid2 chunk (relu)
        gemm(stream, fmidG, gW2 + c * 1024, b2, (c == 0) ? bA : (float*)d_out,
             nullptr, d_out, MG, D_, 1024, FF_, 1,
             0, 0, 0, 0, 0, 1.0f, 0, (c == 0) ? 1 : 0, 1, 0);
    }
}

// Round 7
// 2065.861 us; speedup vs baseline: 4.5820x; 1.0454x over previous
//
#include <hip/hip_runtime.h>

#define B_   32
#define L_   796
#define D_   512
#define H_   8
#define HD_  64
#define FF_  2048
#define CS_  16
#define STR_ 13
#define NC_  61
#define NQT_ 13
#define MC_  976            // NC_*CS_ rows per batch (clip path)
#define QKVS 1536           // fused QKV row stride
#define QS   (0.125f * 1.44269504f)   // 1/sqrt(64) * log2(e)  -> exp2 softmax

typedef __attribute__((ext_vector_type(8))) short short8;
typedef __attribute__((ext_vector_type(4))) float f32x4;

__device__ __forceinline__ unsigned short f2bf(float x) {
    unsigned u = __float_as_uint(x);
    unsigned r = u + 0x7FFFu + ((u >> 16) & 1u);   // RNE
    return (unsigned short)(r >> 16);
}
__device__ __forceinline__ float bf2f(unsigned short h) {
    return __uint_as_float(((unsigned)h) << 16);
}
__device__ __forceinline__ float ex2(float x) {      // native v_exp_f32 (2^x)
    return __builtin_amdgcn_exp2f(x);
}
__device__ __forceinline__ void gload16(const unsigned short* g, unsigned short* l) {
    __builtin_amdgcn_global_load_lds(
        (const __attribute__((address_space(1))) void*)g,
        (__attribute__((address_space(3))) void*)l, 16, 0, 0);
}

// ---------------------------------------------------------------------------
// LayerNorm D=512, f32 in -> bf16 out.
// gather=0: direct rows; gather=1: x_rec remap; gather=2: clip build from x.
// ---------------------------------------------------------------------------
__global__ __launch_bounds__(256) void k_ln(const float* __restrict__ in,
                                            unsigned short* __restrict__ out,
                                            const float* __restrict__ gamma,
                                            const float* __restrict__ beta,
                                            int rows_per_batch, int gstride, int gather)
{
    __shared__ float red[8];
    long long row = blockIdx.x;
    int tid = threadIdx.x;
    int b;
    float v0, v1;
    if (gather == 2) {
        b = (int)(row / MC_);
        int rr = (int)(row % MC_);
        int n = rr >> 4, c = rr & 15;
        long long xb = (long long)b * L_ * D_;
        int d0 = tid, st0, sd0;
        if (d0 < 128) { st0 = n * STR_ + c; sd0 = d0; }
        else { int j = d0 - 128; st0 = n * STR_ + (j & 15); sd0 = 128 + ((j >> 4) << 4) + c; }
        v0 = in[xb + (long long)st0 * D_ + sd0];
        int j1 = tid + 128;                 // (tid+256)-128
        int st1 = n * STR_ + (j1 & 15), sd1 = 128 + ((j1 >> 4) << 4) + c;
        v1 = in[xb + (long long)st1 * D_ + sd1];
    } else {
        long long srow = row;
        if (gather == 1) {
            int p = (int)(row % L_);
            b = (int)(row / L_);
            int ci = p / STR_; if (ci > NC_ - 1) ci = NC_ - 1;
            srow = ((long long)b * NC_ + ci) * CS_ + (p - ci * STR_);
        } else {
            b = (int)(row / rows_per_batch);
        }
        const float* xr = in + srow * D_;
        v0 = xr[tid]; v1 = xr[tid + 256];
    }
    float s = v0 + v1;
#pragma unroll
    for (int off = 1; off < 64; off <<= 1) s += __shfl_xor(s, off);
    if ((tid & 63) == 0) red[tid >> 6] = s;
    __syncthreads();
    float mean = (red[0] + red[1] + red[2] + red[3]) * (1.0f / 512.0f);
    float d0 = v0 - mean, d1 = v1 - mean;
    float vv = d0 * d0 + d1 * d1;
#pragma unroll
    for (int off = 1; off < 64; off <<= 1) vv += __shfl_xor(vv, off);
    if ((tid & 63) == 0) red[4 + (tid >> 6)] = vv;
    __syncthreads();
    float var = (red[4] + red[5] + red[6] + red[7]) * (1.0f / 512.0f);
    float rstd = rsqrtf(var + 1e-6f);
    const float* g  = gamma + (long long)b * gstride;
    const float* bt = beta  + (long long)b * gstride;
    unsigned short* o = out + row * D_;
    o[tid]       = f2bf(d0 * rstd * g[tid]       + bt[tid]);
    o[tid + 256] = f2bf(d1 * rstd * g[tid + 256] + bt[tid + 256]);
}

// ---------------------------------------------------------------------------
// Weight transpose+convert: W f32 [K x N] (row stride rowStride) -> T bf16
// [N][K] (row stride tStride). grid (N/32, K/32, G).
// ---------------------------------------------------------------------------
__global__ __launch_bounds__(256) void k_wt(const float* __restrict__ W,
                                            unsigned short* __restrict__ T,
                                            int rowStride, int tStride,
                                            long long sWb, long long sTb)
{
    __shared__ float t[32][33];
    int z = blockIdx.z;
    const float* Wz = W + (long long)z * sWb;
    unsigned short* Tz = T + (long long)z * sTb;
    int n0 = blockIdx.x << 5, k0 = blockIdx.y << 5;
    int tx = threadIdx.x & 31, ty = threadIdx.x >> 5;
#pragma unroll
    for (int i = 0; i < 4; i++) {
        int k = ty + (i << 3);
        t[k][tx] = Wz[(long long)(k0 + k) * rowStride + n0 + tx];
    }
    __syncthreads();
#pragma unroll
    for (int i = 0; i < 4; i++) {
        int n = ty + (i << 3);
        Tz[(long long)(n0 + n) * tStride + k0 + tx] = f2bf(t[tx][n]);
    }
}

// Stacked transpose of up to 4 square 512x512 tensors x nb batches.
// z = tensor*nb + batch. dst: [batch][tensor*512 + n][512].
__global__ __launch_bounds__(256) void k_wt_stack(const float* __restrict__ Wa,
                                                  const float* __restrict__ Wb,
                                                  const float* __restrict__ Wc,
                                                  const float* __restrict__ Wd,
                                                  unsigned short* __restrict__ T,
                                                  int nb, int ntens, long long sWb)
{
    __shared__ float t[32][33];
    int z = blockIdx.z;
    int tt = z / nb, b = z % nb;
    const float* Wz = (tt == 0 ? Wa : tt == 1 ? Wb : tt == 2 ? Wc : Wd)
                      + (long long)b * sWb;
    unsigned short* Tz = T + ((long long)b * ntens + tt) * (512 * 512);
    int n0 = blockIdx.x << 5, k0 = blockIdx.y << 5;
    int tx = threadIdx.x & 31, ty = threadIdx.x >> 5;
#pragma unroll
    for (int i = 0; i < 4; i++) {
        int k = ty + (i << 3);
        t[k][tx] = Wz[(long long)(k0 + k) * 512 + n0 + tx];
    }
    __syncthreads();
#pragma unroll
    for (int i = 0; i < 4; i++) {
        int n = ty + (i << 3);
        Tz[(long long)(n0 + n) * 512 + k0 + tx] = f2bf(t[tx][n]);
    }
}

// ---------------------------------------------------------------------------
// bf16 MFMA GEMM, global_load_lds staging (pre-swizzled source).
// biasmode: 0 none, 1 single b0[gc], 3 triple 512-col segments (b0|b1|b2).
// alpha for gc<512, alpha1 for gc>=512. resmode: 0 none, 1 f32 res (may
// alias Cout elementwise), 2 clip-gather residual from xg.
// ---------------------------------------------------------------------------
__global__ __launch_bounds__(256) void k_gemm_mfma(
    const unsigned short* __restrict__ A, const unsigned short* __restrict__ WT,
    const float* __restrict__ b0p, const float* __restrict__ b1p,
    const float* __restrict__ b2p,
    const float* res, const float* __restrict__ xg, void* Cout,
    int M, int N, int K, int ldwk,
    long long sAb, long long sWb, long long sBb, long long sRb, long long sCb,
    float alpha, float alpha1, int relu, int biasmode, int resmode, int outbf16)
{
    __shared__ unsigned short lds[16384];
    unsigned short* lA = lds;
    unsigned short* lW = lds + 8192;
    int tid = threadIdx.x;
    int z = blockIdx.z;
    int row0 = blockIdx.y << 7, col0 = blockIdx.x << 7;
    const unsigned short* Ab = A + z * sAb;
    const unsigned short* Wb = WT + z * sWb;

    int w = tid >> 6, lane = tid & 63;
    int wr = (w >> 1) << 6, wc = (w & 1) << 6;
    int l15 = lane & 15, lg = lane >> 4;
    int lrow = lane >> 3, lslot = lane & 7;

    f32x4 acc[4][4];
#pragma unroll
    for (int i = 0; i < 4; i++)
#pragma unroll
        for (int j = 0; j < 4; j++) acc[i][j] = (f32x4)0.f;

    for (int k0 = 0; k0 < K; k0 += 64) {
        __syncthreads();
#pragma unroll
        for (int i = 0; i < 4; i++) {
            int cb = (w << 5) + (i << 3);
            int rr = cb + lrow;
            gload16(Ab + (long long)(row0 + rr) * K + k0 + ((lslot ^ (rr & 7)) << 3),
                    lA + (cb << 6));
            gload16(Wb + (long long)(col0 + rr) * ldwk + k0 + ((lslot ^ (rr & 7)) << 3),
                    lW + (cb << 6));
        }
        __syncthreads();
#pragma unroll
        for (int ks = 0; ks < 2; ks++) {
            short8 af[4], bfr[4];
#pragma unroll
            for (int mf = 0; mf < 4; mf++) {
                int r = wr + (mf << 4) + l15;
                int slot = ((ks << 2) + lg) ^ (r & 7);
                af[mf] = *(const short8*)(lA + (r << 6) + (slot << 3));
            }
#pragma unroll
            for (int nf = 0; nf < 4; nf++) {
                int r = wc + (nf << 4) + l15;
                int slot = ((ks << 2) + lg) ^ (r & 7);
                bfr[nf] = *(const short8*)(lW + (r << 6) + (slot << 3));
            }
#pragma unroll
            for (int mf = 0; mf < 4; mf++)
#pragma unroll
                for (int nf = 0; nf < 4; nf++)
                    acc[mf][nf] = __builtin_amdgcn_mfma_f32_16x16x32_bf16(
                        af[mf], bfr[nf], acc[mf][nf], 0, 0, 0);
        }
    }

#pragma unroll
    for (int mf = 0; mf < 4; mf++) {
#pragma unroll
        for (int reg = 0; reg < 4; reg++) {
            int gr = row0 + wr + (mf << 4) + (lg << 2) + reg;
            if (gr >= M) continue;
#pragma unroll
            for (int nf = 0; nf < 4; nf++) {
                int gc = col0 + wc + (nf << 4) + l15;
                float v = acc[mf][nf][reg];
                if (biasmode == 1) v += b0p[z * sBb + gc];
                else if (biasmode == 3) {
                    const float* bp = gc < 512 ? b0p : (gc < 1024 ? b1p : b2p);
                    v += bp[z * sBb + (gc & 511)];
                }
                v *= (gc < 512) ? alpha : alpha1;
                if (relu) v = fmaxf(v, 0.f);
                if (resmode == 1) {
                    v += res[z * sRb + (long long)gr * N + gc];
                } else if (resmode == 2) {
                    int n = gr >> 4, c = gr & 15;
                    int st, sd;
                    if (gc < 128) { st = n * STR_ + c; sd = gc; }
                    else {
                        int jj = gc - 128;
                        st = n * STR_ + (jj & 15);
                        sd = 128 + ((jj >> 4) << 4) + c;
                    }
                    v += xg[((long long)z * L_ + st) * D_ + sd];
                }
                long long co = z * sCb + (long long)gr * N + gc;
                if (outbf16) ((unsigned short*)Cout)[co] = f2bf(v);
                else         ((float*)Cout)[co] = v;
            }
        }
    }
}

// ---------------------------------------------------------------------------
// Clip attention on fused QKV (stride QKVS, offsets 0/512/1024), exp2 softmax.
// ---------------------------------------------------------------------------
__global__ __launch_bounds__(256) void k_clip_attn(const unsigned short* __restrict__ qkv,
                                                   unsigned short* __restrict__ ctx)
{
    __shared__ float qs[CS_][65], ks[CS_][65], vs[CS_][65], ps[CS_][17];
    int id = blockIdx.x;
    int h = id & (H_ - 1);
    int n = (id / H_) % NC_;
    int b = id / (H_ * NC_);
    long long base = (((long long)b * NC_ + n) * CS_) * QKVS + h * HD_;
    int tid = threadIdx.x;
#pragma unroll
    for (int i = 0; i < 4; i++) {
        int e = tid + i * 256;
        int r = e >> 6, c = e & 63;
        long long ro = base + (long long)r * QKVS + c;
        qs[r][c] = bf2f(qkv[ro]);
        ks[r][c] = bf2f(qkv[ro + 512]);
        vs[r][c] = bf2f(qkv[ro + 1024]);
    }
    __syncthreads();
    int qr = tid >> 4, kc = tid & 15;
    float s = 0.f;
#pragma unroll
    for (int d = 0; d < HD_; d++) s += qs[qr][d] * ks[kc][d];
    float m = s;
#pragma unroll
    for (int off = 1; off < 16; off <<= 1) m = fmaxf(m, __shfl_xor(m, off));
    float e = ex2(s - m);
    float sum = e;
#pragma unroll
    for (int off = 1; off < 16; off <<= 1) sum += __shfl_xor(sum, off);
    ps[qr][kc] = e / sum;
    __syncthreads();
    int dg = (tid & 15) * 4;
    float o0 = 0, o1 = 0, o2 = 0, o3 = 0;
#pragma unroll
    for (int kk = 0; kk < CS_; kk++) {
        float pp = ps[qr][kk];
        o0 += pp * vs[kk][dg + 0];
        o1 += pp * vs[kk][dg + 1];
        o2 += pp * vs[kk][dg + 2];
        o3 += pp * vs[kk][dg + 3];
    }
    long long ob = ((((long long)b * NC_ + n) * CS_) + qr) * D_ + h * HD_ + dg;
    ctx[ob + 0] = f2bf(o0);
    ctx[ob + 1] = f2bf(o1);
    ctx[ob + 2] = f2bf(o2);
    ctx[ob + 3] = f2bf(o3);
}

// ---------------------------------------------------------------------------
// Global flash attention (MFMA, exp2 softmax) on fused QKV buffer.
// ---------------------------------------------------------------------------
__global__ __launch_bounds__(256) void k_flash_mfma(
    const unsigned short* __restrict__ qkv,
    unsigned short* __restrict__ out)
{
    __shared__ unsigned short lQ[4096], lK[4096], lV[4096], lP[4096];
    int id = blockIdx.x;
    int qt = id % NQT_;
    int h  = (id / NQT_) & (H_ - 1);
    int b  = id / (NQT_ * H_);
    int tid = threadIdx.x;
    int q0 = qt * 64;
    long long base = (long long)b * L_ * QKVS + h * HD_;

    int w = tid >> 6, lane = tid & 63;
    int l15 = lane & 15, lg = lane >> 4;
    int lrow = lane >> 3, lslot = lane & 7;
    int srow = lane;
    int sd0  = w << 4;

#pragma unroll
    for (int i = 0; i < 2; i++) {
        int cb = (w << 4) + (i << 3);
        int rr = cb + lrow;
        gload16(qkv + base + (long long)(q0 + rr) * QKVS + ((lslot ^ (rr & 7)) << 3),
                lQ + (cb << 6));
    }
    __syncthreads();

    int qrow = (w << 4) + l15;
    short8 qf[2];
#pragma unroll
    for (int ks = 0; ks < 2; ks++) {
        int slot = (ks << 2) + lg;
        qf[ks] = *(const short8*)(lQ + qrow * 64 + ((slot ^ (qrow & 7)) << 3));
    }
    unsigned short* lPw = lP + (w << 10);

    float m[4], l[4];
    f32x4 oacc[4];
#pragma unroll
    for (int r = 0; r < 4; r++) { m[r] = -1e30f; l[r] = 0.f; }
#pragma unroll
    for (int nf = 0; nf < 4; nf++) oacc[nf] = (f32x4)0.f;

    for (int kt = 0; kt < NQT_; kt++) {
        int k0 = kt * 64;
        __syncthreads();
#pragma unroll
        for (int i = 0; i < 2; i++) {
            int cb = (w << 4) + (i << 3);
            int rr = cb + lrow;
            gload16(qkv + base + 512 + (long long)(k0 + rr) * QKVS + ((lslot ^ (rr & 7)) << 3),
                    lK + (cb << 6));
        }
        {
            int gr = k0 + srow;
            short8 v0 = (short8)0, v1 = (short8)0;
            if (gr < L_) {
                const unsigned short* pv = qkv + base + 1024 + (long long)gr * QKVS + sd0;
                v0 = *(const short8*)pv;
                v1 = *(const short8*)(pv + 8);
            }
            int ts = srow >> 3, t7 = srow & 7;
#pragma unroll
            for (int i = 0; i < 8; i++) {
                int d = sd0 + i;
                lV[d * 64 + ((ts ^ (d & 7)) << 3) + t7] = (unsigned short)v0[i];
            }
#pragma unroll
            for (int i = 0; i < 8; i++) {
                int d = sd0 + 8 + i;
                lV[d * 64 + ((ts ^ (d & 7)) << 3) + t7] = (unsigned short)v1[i];
            }
        }
        __syncthreads();

        f32x4 acc[4];
#pragma unroll
        for (int nf = 0; nf < 4; nf++) {
            acc[nf] = (f32x4)0.f;
            int tok = (nf << 4) + l15;
            int key = tok & 7;
#pragma unroll
            for (int ks = 0; ks < 2; ks++) {
                int slot = (ks << 2) + lg;
                short8 kf = *(const short8*)(lK + tok * 64 + ((slot ^ key) << 3));
                acc[nf] = __builtin_amdgcn_mfma_f32_16x16x32_bf16(qf[ks], kf, acc[nf], 0, 0, 0);
            }
        }
        float rm[4];
#pragma unroll
        for (int r = 0; r < 4; r++) rm[r] = -1e30f;
#pragma unroll
        for (int nf = 0; nf < 4; nf++) {
            bool oob = (k0 + (nf << 4) + l15) >= L_;
#pragma unroll
            for (int r = 0; r < 4; r++) {
                if (oob) acc[nf][r] = -1e30f;
                rm[r] = fmaxf(rm[r], acc[nf][r]);
            }
        }
#pragma unroll
        for (int off = 1; off < 16; off <<= 1) {
#pragma unroll
            for (int r = 0; r < 4; r++) rm[r] = fmaxf(rm[r], __shfl_xor(rm[r], off));
        }
        float sc[4], ls[4];
#pragma unroll
        for (int r = 0; r < 4; r++) {
            float mn = fmaxf(m[r], rm[r]);
            sc[r] = ex2(m[r] - mn);
            m[r] = mn;
            ls[r] = 0.f;
        }
#pragma unroll
        for (int nf = 0; nf < 4; nf++) {
            int tok = (nf << 4) + l15;
            int slot = tok >> 3, t7 = tok & 7;
#pragma unroll
            for (int r = 0; r < 4; r++) {
                float p = ex2(acc[nf][r] - m[r]);
                ls[r] += p;
                int row = (lg << 2) + r;
                lPw[row * 64 + ((slot ^ (row & 7)) << 3) + t7] = f2bf(p);
            }
        }
#pragma unroll
        for (int off = 1; off < 16; off <<= 1) {
#pragma unroll
            for (int r = 0; r < 4; r++) ls[r] += __shfl_xor(ls[r], off);
        }
#pragma unroll
        for (int r = 0; r < 4; r++) l[r] = l[r] * sc[r] + ls[r];
#pragma unroll
        for (int nf = 0; nf < 4; nf++) {
#pragma unroll
            for (int r = 0; r < 4; r++) oacc[nf][r] *= sc[r];
        }
#pragma unroll
        for (int ks = 0; ks < 2; ks++) {
            int slot = (ks << 2) + lg;
            short8 pa = *(const short8*)(lPw + l15 * 64 + ((slot ^ (l15 & 7)) << 3));
#pragma unroll
            for (int nf = 0; nf < 4; nf++) {
                int d = (nf << 4) + l15;
                short8 vb = *(const short8*)(lV + d * 64 + ((slot ^ (d & 7)) << 3));
                oacc[nf] = __builtin_amdgcn_mfma_f32_16x16x32_bf16(pa, vb, oacc[nf], 0, 0, 0);
            }
        }
    }
    long long obase = (long long)b * L_ * D_ + h * HD_;
#pragma unroll
    for (int r = 0; r < 4; r++) {
        int gr = q0 + (w << 4) + (lg << 2) + r;
        if (gr >= L_) continue;
        float inv = 1.f / l[r];
        long long ob = obase + (long long)gr * D_;
#pragma unroll
        for (int nf = 0; nf < 4; nf++)
            out[ob + (nf << 4) + l15] = f2bf(oacc[nf][r] * inv);
    }
}

// ---------------------------------------------------------------------------
static inline void gemm(hipStream_t st, const unsigned short* A, const unsigned short* WTp,
                        const float* b0, const float* b1, const float* b2,
                        const float* res, const float* xg, void* C,
                        int M, int N, int K, int ldwk, int G,
                        long long sAb, long long sWb, long long sBb,
                        long long sRb, long long sCb,
                        float alpha, float alpha1, int relu, int biasmode,
                        int resmode, int outbf16)
{
    dim3 grid(N / 128, (M + 127) / 128, G);
    k_gemm_mfma<<<grid, 256, 0, st>>>(A, WTp, b0, b1, b2, res, xg, C,
                                      M, N, K, ldwk, sAb, sWb, sBb, sRb, sCb,
                                      alpha, alpha1, relu, biasmode, resmode, outbf16);
}

extern "C" void kernel_launch(void* const* d_in, const int* in_sizes, int n_in,
                              void* d_out, int out_size, void* d_ws, size_t ws_size,
                              hipStream_t stream)
{
    (void)in_sizes; (void)n_in; (void)out_size; (void)ws_size;
    const float* x      = (const float*)d_in[0];
    const float* g_ln_g = (const float*)d_in[2];
    const float* g_ln_b = (const float*)d_in[3];
    const float* Wq = (const float*)d_in[4];
    const float* Wk = (const float*)d_in[5];
    const float* Wv = (const float*)d_in[6];
    const float* Wo = (const float*)d_in[7];
    const float* bq = (const float*)d_in[8];
    const float* bk = (const float*)d_in[9];
    const float* bv = (const float*)d_in[10];
    const float* bo = (const float*)d_in[11];
    const float* f_ln_g = (const float*)d_in[12];
    const float* f_ln_b = (const float*)d_in[13];
    const float* W1 = (const float*)d_in[14];
    const float* b1 = (const float*)d_in[15];
    const float* W2 = (const float*)d_in[16];
    const float* b2 = (const float*)d_in[17];
    const float* c_ln_g = (const float*)d_in[18];
    const float* c_ln_b = (const float*)d_in[19];
    const float* cWq = (const float*)d_in[20];
    const float* cWk = (const float*)d_in[21];
    const float* cWv = (const float*)d_in[22];
    const float* cWo = (const float*)d_in[23];
    const float* cbq = (const float*)d_in[24];
    const float* cbk = (const float*)d_in[25];
    const float* cbv = (const float*)d_in[26];
    const float* cbo = (const float*)d_in[27];
    const float* cf_ln_g = (const float*)d_in[28];
    const float* cf_ln_b = (const float*)d_in[29];
    const float* cW1 = (const float*)d_in[30];
    const float* cb1 = (const float*)d_in[31];
    const float* cW2 = (const float*)d_in[32];
    const float* cb2 = (const float*)d_in[33];

    // ---- workspace layout (236 MB) ----
    char* wsb = (char*)d_ws;
    float*          bA   = (float*)wsb;                              // 64MB f32: hcl -> clips_out -> h
    unsigned short* bB   = (unsigned short*)(wsb + (64ll  << 20));   // 32MB bf16 activations
    unsigned short* bQKV = (unsigned short*)(wsb + (96ll  << 20));   // 92MB: fused qkv / fmid chunks
    unsigned short* wT   = (unsigned short*)(wsb + (188ll << 20));   // 48MB: weight transposes

    const long long sA   = (long long)MC_ * D_;
    const long long sQKV = (long long)MC_ * QKVS;
    const long long sWW  = (long long)D_ * D_;
    const int MG = B_ * L_;

    // ================= clip path =================
    k_ln<<<B_ * MC_, 256, 0, stream>>>(x, bB, c_ln_g, c_ln_b, MC_, D_, 2);   // cn (fused gather)
    k_wt_stack<<<dim3(16, 16, 3 * B_), 256, 0, stream>>>(cWq, cWk, cWv, nullptr,
                                                         wT, B_, 3, sWW);
    gemm(stream, bB, wT, cbq, cbk, cbv, nullptr, nullptr, bQKV,
         MC_, QKVS, D_, D_, B_, sA, 3 * sWW, D_, 0, sQKV,
         QS, 1.0f, 0, 3, 0, 1);                                              // fused clip QKV
    k_clip_attn<<<B_ * NC_ * H_, 256, 0, stream>>>(bQKV, bB);                // ctx -> bB
    k_wt<<<dim3(16, 16, B_), 256, 0, stream>>>(cWo, wT, D_, D_, sWW, sWW);
    gemm(stream, bB, wT, cbo, nullptr, nullptr, nullptr, x, bA,
         MC_, D_, D_, D_, B_, sA, sWW, D_, 0, sA,
         1.0f, 1.0f, 0, 1, 2, 0);                                            // hcl f32 -> bA
    k_ln<<<B_ * MC_, 256, 0, stream>>>(bA, bB, cf_ln_g, cf_ln_b, MC_, D_, 0); // fn
    for (int c = 0; c < 2; c++) {   // clip FFN, 2 chunks of 1024
        k_wt<<<dim3(32, 16, B_), 256, 0, stream>>>(cW1 + c * 1024, wT, FF_, D_,
                                                   (long long)D_ * FF_, 1024ll * D_);
        gemm(stream, bB, wT, cb1 + c * 1024, nullptr, nullptr, nullptr, nullptr, bQKV,
             MC_, 1024, D_, D_, B_, sA, 1024ll * D_, FF_, 0, (long long)MC_ * 1024,
             1.0f, 1.0f, 1, 1, 0, 1);                                        // fmid chunk (relu)
        k_wt<<<dim3(16, 32, B_), 256, 0, stream>>>(cW2 + (long long)c * 1024 * D_, wT,
                                                   D_, 1024, (long long)FF_ * D_,
                                                   (long long)D_ * 1024);
        gemm(stream, bQKV, wT, cb2, nullptr, nullptr, bA, nullptr, bA,
             MC_, D_, 1024, 1024, B_, (long long)MC_ * 1024, (long long)D_ * 1024,
             D_, sA, sA, 1.0f, 1.0f, 0, (c == 0) ? 1 : 0, 1, 0);             // clips_out in-place bA
    }

    // ================= global path =================
    unsigned short* gQKVO = wT;                    // [2048][512]
    unsigned short* gW1   = wT + 4 * 262144;       // [2048][512]
    unsigned short* gW2   = wT + 8 * 262144;       // [512][2048]
    k_wt_stack<<<dim3(16, 16, 4), 256, 0, stream>>>(Wq, Wk, Wv, Wo, gQKVO, 1, 4, 0);
    k_wt<<<dim3(64, 16, 1), 256, 0, stream>>>(W1, gW1, FF_, D_, 0, 0);
    k_wt<<<dim3(16, 64, 1), 256, 0, stream>>>(W2, gW2, D_, FF_, 0, 0);

    k_ln<<<MG, 256, 0, stream>>>(bA, bB, g_ln_g, g_ln_b, L_, 0, 1);          // xn (x_rec gather)
    gemm(stream, bB, gQKVO, bq, bk, bv, nullptr, nullptr, bQKV,
         MG, QKVS, D_, D_, 1, 0, 0, 0, 0, 0,
         QS, 1.0f, 0, 3, 0, 1);                                              // fused global QKV
    k_flash_mfma<<<B_ * H_ * NQT_, 256, 0, stream>>>(bQKV, bB);              // ctx2 -> bB
    gemm(stream, bB, gQKVO + 3 * 262144, bo, nullptr, nullptr, x, nullptr, bA,
         MG, D_, D_, D_, 1, 0, 0, 0, 0, 0,
         1.0f, 1.0f, 0, 1, 1, 0);                                            // h f32 -> bA (res=x)
    k_ln<<<MG, 256, 0, stream>>>(bA, bB, f_ln_g, f_ln_b, MG, 0, 0);          // hn
    for (int c = 0; c < 2; c++) {    // global FFN, 2 chunks of 1024
        gemm(stream, bB, gW1 + (long long)c * 1024 * 512, b1 + c * 1024,
             nullptr, nullptr, nullptr, nullptr, bQKV,
             MG, 1024, D_, D_, 1, 0, 0, 0, 0, 0,
             1.0f, 1.0f, 1, 1, 0, 1);                                        // mid2 chunk (relu)
        gemm(stream, bQKV, gW2 + c * 1024, b2, nullptr, nullptr,
             (c == 0) ? bA : (float*)d_out, nullptr, d_out,
             MG, D_, 1024, FF_, 1, 0, 0, 0, 0, 0,
             1.0f, 1.0f, 0, (c == 0) ? 1 : 0, 1, 0);                         // out (in-place c=1)
    }
}

// Round 8
// 2000.496 us; speedup vs baseline: 4.7317x; 1.0327x over previous
//
#include <hip/hip_runtime.h>

#define B_   32
#define L_   796
#define D_   512
#define H_   8
#define HD_  64
#define FF_  2048
#define CS_  16
#define STR_ 13
#define NC_  61
#define NQT_ 13
#define MC_  976            // NC_*CS_ rows per batch (clip path)
#define QKVS 1536           // fused QKV row stride
#define QS   (0.125f * 1.44269504f)   // 1/sqrt(64) * log2(e)  -> exp2 softmax

typedef __attribute__((ext_vector_type(8))) short short8;
typedef __attribute__((ext_vector_type(4))) float f32x4;

__device__ __forceinline__ unsigned short f2bf(float x) {
    unsigned u = __float_as_uint(x);
    unsigned r = u + 0x7FFFu + ((u >> 16) & 1u);   // RNE
    return (unsigned short)(r >> 16);
}
__device__ __forceinline__ float bf2f(unsigned short h) {
    return __uint_as_float(((unsigned)h) << 16);
}
__device__ __forceinline__ float ex2(float x) {      // native v_exp_f32 (2^x)
    return __builtin_amdgcn_exp2f(x);
}
__device__ __forceinline__ void gload16(const unsigned short* g, unsigned short* l) {
    __builtin_amdgcn_global_load_lds(
        (const __attribute__((address_space(1))) void*)g,
        (__attribute__((address_space(3))) void*)l, 16, 0, 0);
}

// ---------------------------------------------------------------------------
// LayerNorm D=512, f32 in -> bf16 out.
// gather=0: direct rows; gather=1: x_rec remap; gather=2: clip build from x.
// ---------------------------------------------------------------------------
__global__ __launch_bounds__(256) void k_ln(const float* __restrict__ in,
                                            unsigned short* __restrict__ out,
                                            const float* __restrict__ gamma,
                                            const float* __restrict__ beta,
                                            int rows_per_batch, int gstride, int gather)
{
    __shared__ float red[8];
    long long row = blockIdx.x;
    int tid = threadIdx.x;
    int b;
    float v0, v1;
    if (gather == 2) {
        b = (int)(row / MC_);
        int rr = (int)(row % MC_);
        int n = rr >> 4, c = rr & 15;
        long long xb = (long long)b * L_ * D_;
        int d0 = tid, st0, sd0;
        if (d0 < 128) { st0 = n * STR_ + c; sd0 = d0; }
        else { int j = d0 - 128; st0 = n * STR_ + (j & 15); sd0 = 128 + ((j >> 4) << 4) + c; }
        v0 = in[xb + (long long)st0 * D_ + sd0];
        int j1 = tid + 128;                 // (tid+256)-128
        int st1 = n * STR_ + (j1 & 15), sd1 = 128 + ((j1 >> 4) << 4) + c;
        v1 = in[xb + (long long)st1 * D_ + sd1];
    } else {
        long long srow = row;
        if (gather == 1) {
            int p = (int)(row % L_);
            b = (int)(row / L_);
            int ci = p / STR_; if (ci > NC_ - 1) ci = NC_ - 1;
            srow = ((long long)b * NC_ + ci) * CS_ + (p - ci * STR_);
        } else {
            b = (int)(row / rows_per_batch);
        }
        const float* xr = in + srow * D_;
        v0 = xr[tid]; v1 = xr[tid + 256];
    }
    float s = v0 + v1;
#pragma unroll
    for (int off = 1; off < 64; off <<= 1) s += __shfl_xor(s, off);
    if ((tid & 63) == 0) red[tid >> 6] = s;
    __syncthreads();
    float mean = (red[0] + red[1] + red[2] + red[3]) * (1.0f / 512.0f);
    float d0 = v0 - mean, d1 = v1 - mean;
    float vv = d0 * d0 + d1 * d1;
#pragma unroll
    for (int off = 1; off < 64; off <<= 1) vv += __shfl_xor(vv, off);
    if ((tid & 63) == 0) red[4 + (tid >> 6)] = vv;
    __syncthreads();
    float var = (red[4] + red[5] + red[6] + red[7]) * (1.0f / 512.0f);
    float rstd = rsqrtf(var + 1e-6f);
    const float* g  = gamma + (long long)b * gstride;
    const float* bt = beta  + (long long)b * gstride;
    unsigned short* o = out + row * D_;
    o[tid]       = f2bf(d0 * rstd * g[tid]       + bt[tid]);
    o[tid + 256] = f2bf(d1 * rstd * g[tid + 256] + bt[tid + 256]);
}

// ---------------------------------------------------------------------------
// Weight transpose+convert: W f32 [K x N] (row stride rowStride) -> T bf16
// [N][K] (row stride tStride). grid (N/32, K/32, G).
// ---------------------------------------------------------------------------
__global__ __launch_bounds__(256) void k_wt(const float* __restrict__ W,
                                            unsigned short* __restrict__ T,
                                            int rowStride, int tStride,
                                            long long sWb, long long sTb)
{
    __shared__ float t[32][33];
    int z = blockIdx.z;
    const float* Wz = W + (long long)z * sWb;
    unsigned short* Tz = T + (long long)z * sTb;
    int n0 = blockIdx.x << 5, k0 = blockIdx.y << 5;
    int tx = threadIdx.x & 31, ty = threadIdx.x >> 5;
#pragma unroll
    for (int i = 0; i < 4; i++) {
        int k = ty + (i << 3);
        t[k][tx] = Wz[(long long)(k0 + k) * rowStride + n0 + tx];
    }
    __syncthreads();
#pragma unroll
    for (int i = 0; i < 4; i++) {
        int n = ty + (i << 3);
        Tz[(long long)(n0 + n) * tStride + k0 + tx] = f2bf(t[tx][n]);
    }
}

// Stacked transpose of up to 4 square 512x512 tensors x nb batches.
// z = tensor*nb + batch. dst: [batch][tensor*512 + n][512].
__global__ __launch_bounds__(256) void k_wt_stack(const float* __restrict__ Wa,
                                                  const float* __restrict__ Wb,
                                                  const float* __restrict__ Wc,
                                                  const float* __restrict__ Wd,
                                                  unsigned short* __restrict__ T,
                                                  int nb, int ntens, long long sWb)
{
    __shared__ float t[32][33];
    int z = blockIdx.z;
    int tt = z / nb, b = z % nb;
    const float* Wz = (tt == 0 ? Wa : tt == 1 ? Wb : tt == 2 ? Wc : Wd)
                      + (long long)b * sWb;
    unsigned short* Tz = T + ((long long)b * ntens + tt) * (512 * 512);
    int n0 = blockIdx.x << 5, k0 = blockIdx.y << 5;
    int tx = threadIdx.x & 31, ty = threadIdx.x >> 5;
#pragma unroll
    for (int i = 0; i < 4; i++) {
        int k = ty + (i << 3);
        t[k][tx] = Wz[(long long)(k0 + k) * 512 + n0 + tx];
    }
    __syncthreads();
#pragma unroll
    for (int i = 0; i < 4; i++) {
        int n = ty + (i << 3);
        Tz[(long long)(n0 + n) * 512 + k0 + tx] = f2bf(t[tx][n]);
    }
}

// ---------------------------------------------------------------------------
// bf16 MFMA GEMM, global_load_lds staging (pre-swizzled source).
// 1D grid with XCD-aware block swizzle (T1):
//   mode 0 (batched): xcd = z&7 -> each XCD owns whole batches (A_z+W_z L2-fit)
//   mode 1 (G==1):    xcd = y&7 -> all col-blocks of a row-panel on one XCD
// bid = inner*8 + xcd. mode0: inner=((z>>3)*NYd + y)*NX + x (NZ%8==0).
// mode1: inner=(y>>3)*NX + x (NY padded to %8==0; OOB row-tiles return).
// biasmode: 0 none, 1 single b0[gc], 3 triple 512-col segments (b0|b1|b2).
// alpha for gc<512, alpha1 for gc>=512. resmode: 0 none, 1 f32 res (may
// alias Cout elementwise), 2 clip-gather residual from xg.
// ---------------------------------------------------------------------------
__global__ __launch_bounds__(256) void k_gemm_mfma(
    const unsigned short* __restrict__ A, const unsigned short* __restrict__ WT,
    const float* __restrict__ b0p, const float* __restrict__ b1p,
    const float* __restrict__ b2p,
    const float* res, const float* __restrict__ xg, void* Cout,
    int M, int N, int K, int ldwk, int NX, int NYd, int mode,
    long long sAb, long long sWb, long long sBb, long long sRb, long long sCb,
    float alpha, float alpha1, int relu, int biasmode, int resmode, int outbf16)
{
    __shared__ unsigned short lds[16384];
    unsigned short* lA = lds;
    unsigned short* lW = lds + 8192;
    int tid = threadIdx.x;

    // ---- XCD-aware decode ----
    int bid = blockIdx.x;
    int xcd = bid & 7, inner = bid >> 3;
    int x = inner % NX, t = inner / NX;
    int y, z;
    if (mode == 0) { y = t % NYd; z = (t / NYd) * 8 + xcd; }
    else           { y = t * 8 + xcd; z = 0; }
    int row0 = y << 7, col0 = x << 7;
    if (row0 >= M) return;                 // padded row-tile (mode 1)

    const unsigned short* Ab = A + z * sAb;
    const unsigned short* Wb = WT + z * sWb;

    int w = tid >> 6, lane = tid & 63;
    int wr = (w >> 1) << 6, wc = (w & 1) << 6;
    int l15 = lane & 15, lg = lane >> 4;
    int lrow = lane >> 3, lslot = lane & 7;

    f32x4 acc[4][4];
#pragma unroll
    for (int i = 0; i < 4; i++)
#pragma unroll
        for (int j = 0; j < 4; j++) acc[i][j] = (f32x4)0.f;

    for (int k0 = 0; k0 < K; k0 += 64) {
        __syncthreads();
#pragma unroll
        for (int i = 0; i < 4; i++) {
            int cb = (w << 5) + (i << 3);
            int rr = cb + lrow;
            gload16(Ab + (long long)(row0 + rr) * K + k0 + ((lslot ^ (rr & 7)) << 3),
                    lA + (cb << 6));
            gload16(Wb + (long long)(col0 + rr) * ldwk + k0 + ((lslot ^ (rr & 7)) << 3),
                    lW + (cb << 6));
        }
        __syncthreads();
#pragma unroll
        for (int ks = 0; ks < 2; ks++) {
            short8 af[4], bfr[4];
#pragma unroll
            for (int mf = 0; mf < 4; mf++) {
                int r = wr + (mf << 4) + l15;
                int slot = ((ks << 2) + lg) ^ (r & 7);
                af[mf] = *(const short8*)(lA + (r << 6) + (slot << 3));
            }
#pragma unroll
            for (int nf = 0; nf < 4; nf++) {
                int r = wc + (nf << 4) + l15;
                int slot = ((ks << 2) + lg) ^ (r & 7);
                bfr[nf] = *(const short8*)(lW + (r << 6) + (slot << 3));
            }
#pragma unroll
            for (int mf = 0; mf < 4; mf++)
#pragma unroll
                for (int nf = 0; nf < 4; nf++)
                    acc[mf][nf] = __builtin_amdgcn_mfma_f32_16x16x32_bf16(
                        af[mf], bfr[nf], acc[mf][nf], 0, 0, 0);
        }
    }

#pragma unroll
    for (int mf = 0; mf < 4; mf++) {
#pragma unroll
        for (int reg = 0; reg < 4; reg++) {
            int gr = row0 + wr + (mf << 4) + (lg << 2) + reg;
            if (gr >= M) continue;
#pragma unroll
            for (int nf = 0; nf < 4; nf++) {
                int gc = col0 + wc + (nf << 4) + l15;
                float v = acc[mf][nf][reg];
                if (biasmode == 1) v += b0p[z * sBb + gc];
                else if (biasmode == 3) {
                    const float* bp = gc < 512 ? b0p : (gc < 1024 ? b1p : b2p);
                    v += bp[z * sBb + (gc & 511)];
                }
                v *= (gc < 512) ? alpha : alpha1;
                if (relu) v = fmaxf(v, 0.f);
                if (resmode == 1) {
                    v += res[z * sRb + (long long)gr * N + gc];
                } else if (resmode == 2) {
                    int n = gr >> 4, c = gr & 15;
                    int st, sd;
                    if (gc < 128) { st = n * STR_ + c; sd = gc; }
                    else {
                        int jj = gc - 128;
                        st = n * STR_ + (jj & 15);
                        sd = 128 + ((jj >> 4) << 4) + c;
                    }
                    v += xg[((long long)z * L_ + st) * D_ + sd];
                }
                long long co = z * sCb + (long long)gr * N + gc;
                if (outbf16) ((unsigned short*)Cout)[co] = f2bf(v);
                else         ((float*)Cout)[co] = v;
            }
        }
    }
}

// ---------------------------------------------------------------------------
// Clip attention on fused QKV (stride QKVS, offsets 0/512/1024), exp2 softmax.
// (no cross-block reuse -> no XCD swizzle needed)
// ---------------------------------------------------------------------------
__global__ __launch_bounds__(256) void k_clip_attn(const unsigned short* __restrict__ qkv,
                                                   unsigned short* __restrict__ ctx)
{
    __shared__ float qs[CS_][65], ks[CS_][65], vs[CS_][65], ps[CS_][17];
    int id = blockIdx.x;
    int h = id & (H_ - 1);
    int n = (id / H_) % NC_;
    int b = id / (H_ * NC_);
    long long base = (((long long)b * NC_ + n) * CS_) * QKVS + h * HD_;
    int tid = threadIdx.x;
#pragma unroll
    for (int i = 0; i < 4; i++) {
        int e = tid + i * 256;
        int r = e >> 6, c = e & 63;
        long long ro = base + (long long)r * QKVS + c;
        qs[r][c] = bf2f(qkv[ro]);
        ks[r][c] = bf2f(qkv[ro + 512]);
        vs[r][c] = bf2f(qkv[ro + 1024]);
    }
    __syncthreads();
    int qr = tid >> 4, kc = tid & 15;
    float s = 0.f;
#pragma unroll
    for (int d = 0; d < HD_; d++) s += qs[qr][d] * ks[kc][d];
    float m = s;
#pragma unroll
    for (int off = 1; off < 16; off <<= 1) m = fmaxf(m, __shfl_xor(m, off));
    float e = ex2(s - m);
    float sum = e;
#pragma unroll
    for (int off = 1; off < 16; off <<= 1) sum += __shfl_xor(sum, off);
    ps[qr][kc] = e / sum;
    __syncthreads();
    int dg = (tid & 15) * 4;
    float o0 = 0, o1 = 0, o2 = 0, o3 = 0;
#pragma unroll
    for (int kk = 0; kk < CS_; kk++) {
        float pp = ps[qr][kk];
        o0 += pp * vs[kk][dg + 0];
        o1 += pp * vs[kk][dg + 1];
        o2 += pp * vs[kk][dg + 2];
        o3 += pp * vs[kk][dg + 3];
    }
    long long ob = ((((long long)b * NC_ + n) * CS_) + qr) * D_ + h * HD_ + dg;
    ctx[ob + 0] = f2bf(o0);
    ctx[ob + 1] = f2bf(o1);
    ctx[ob + 2] = f2bf(o2);
    ctx[ob + 3] = f2bf(o3);
}

// ---------------------------------------------------------------------------
// Global flash attention (MFMA, exp2 softmax) on fused QKV buffer.
// XCD swizzle: bid = (b*NQT + qt)*8 + h -> all q-tiles of (b,h) on one XCD
// (K/V panels fetched once into that XCD's L2).
// ---------------------------------------------------------------------------
__global__ __launch_bounds__(256) void k_flash_mfma(
    const unsigned short* __restrict__ qkv,
    unsigned short* __restrict__ out)
{
    __shared__ unsigned short lQ[4096], lK[4096], lV[4096], lP[4096];
    int bid = blockIdx.x;
    int h  = bid & 7;                 // = (b*8+h)&7, partition by head
    int inner = bid >> 3;
    int qt = inner % NQT_;
    int b  = inner / NQT_;
    int tid = threadIdx.x;
    int q0 = qt * 64;
    long long base = (long long)b * L_ * QKVS + h * HD_;

    int w = tid >> 6, lane = tid & 63;
    int l15 = lane & 15, lg = lane >> 4;
    int lrow = lane >> 3, lslot = lane & 7;
    int srow = lane;
    int sd0  = w << 4;

#pragma unroll
    for (int i = 0; i < 2; i++) {
        int cb = (w << 4) + (i << 3);
        int rr = cb + lrow;
        gload16(qkv + base + (long long)(q0 + rr) * QKVS + ((lslot ^ (rr & 7)) << 3),
                lQ + (cb << 6));
    }
    __syncthreads();

    int qrow = (w << 4) + l15;
    short8 qf[2];
#pragma unroll
    for (int ks = 0; ks < 2; ks++) {
        int slot = (ks << 2) + lg;
        qf[ks] = *(const short8*)(lQ + qrow * 64 + ((slot ^ (qrow & 7)) << 3));
    }
    unsigned short* lPw = lP + (w << 10);

    float m[4], l[4];
    f32x4 oacc[4];
#pragma unroll
    for (int r = 0; r < 4; r++) { m[r] = -1e30f; l[r] = 0.f; }
#pragma unroll
    for (int nf = 0; nf < 4; nf++) oacc[nf] = (f32x4)0.f;

    for (int kt = 0; kt < NQT_; kt++) {
        int k0 = kt * 64;
        __syncthreads();
#pragma unroll
        for (int i = 0; i < 2; i++) {
            int cb = (w << 4) + (i << 3);
            int rr = cb + lrow;
            gload16(qkv + base + 512 + (long long)(k0 + rr) * QKVS + ((lslot ^ (rr & 7)) << 3),
                    lK + (cb << 6));
        }
        {
            int gr = k0 + srow;
            short8 v0 = (short8)0, v1 = (short8)0;
            if (gr < L_) {
                const unsigned short* pv = qkv + base + 1024 + (long long)gr * QKVS + sd0;
                v0 = *(const short8*)pv;
                v1 = *(const short8*)(pv + 8);
            }
            int ts = srow >> 3, t7 = srow & 7;
#pragma unroll
            for (int i = 0; i < 8; i++) {
                int d = sd0 + i;
                lV[d * 64 + ((ts ^ (d & 7)) << 3) + t7] = (unsigned short)v0[i];
            }
#pragma unroll
            for (int i = 0; i < 8; i++) {
                int d = sd0 + 8 + i;
                lV[d * 64 + ((ts ^ (d & 7)) << 3) + t7] = (unsigned short)v1[i];
            }
        }
        __syncthreads();

        f32x4 acc[4];
#pragma unroll
        for (int nf = 0; nf < 4; nf++) {
            acc[nf] = (f32x4)0.f;
            int tok = (nf << 4) + l15;
            int key = tok & 7;
#pragma unroll
            for (int ks = 0; ks < 2; ks++) {
                int slot = (ks << 2) + lg;
                short8 kf = *(const short8*)(lK + tok * 64 + ((slot ^ key) << 3));
                acc[nf] = __builtin_amdgcn_mfma_f32_16x16x32_bf16(qf[ks], kf, acc[nf], 0, 0, 0);
            }
        }
        float rm[4];
#pragma unroll
        for (int r = 0; r < 4; r++) rm[r] = -1e30f;
#pragma unroll
        for (int nf = 0; nf < 4; nf++) {
            bool oob = (k0 + (nf << 4) + l15) >= L_;
#pragma unroll
            for (int r = 0; r < 4; r++) {
                if (oob) acc[nf][r] = -1e30f;
                rm[r] = fmaxf(rm[r], acc[nf][r]);
            }
        }
#pragma unroll
        for (int off = 1; off < 16; off <<= 1) {
#pragma unroll
            for (int r = 0; r < 4; r++) rm[r] = fmaxf(rm[r], __shfl_xor(rm[r], off));
        }
        float sc[4], ls[4];
#pragma unroll
        for (int r = 0; r < 4; r++) {
            float mn = fmaxf(m[r], rm[r]);
            sc[r] = ex2(m[r] - mn);
            m[r] = mn;
            ls[r] = 0.f;
        }
#pragma unroll
        for (int nf = 0; nf < 4; nf++) {
            int tok = (nf << 4) + l15;
            int slot = tok >> 3, t7 = tok & 7;
#pragma unroll
            for (int r = 0; r < 4; r++) {
                float p = ex2(acc[nf][r] - m[r]);
                ls[r] += p;
                int row = (lg << 2) + r;
                lPw[row * 64 + ((slot ^ (row & 7)) << 3) + t7] = f2bf(p);
            }
        }
#pragma unroll
        for (int off = 1; off < 16; off <<= 1) {
#pragma unroll
            for (int r = 0; r < 4; r++) ls[r] += __shfl_xor(ls[r], off);
        }
#pragma unroll
        for (int r = 0; r < 4; r++) l[r] = l[r] * sc[r] + ls[r];
#pragma unroll
        for (int nf = 0; nf < 4; nf++) {
#pragma unroll
            for (int r = 0; r < 4; r++) oacc[nf][r] *= sc[r];
        }
#pragma unroll
        for (int ks = 0; ks < 2; ks++) {
            int slot = (ks << 2) + lg;
            short8 pa = *(const short8*)(lPw + l15 * 64 + ((slot ^ (l15 & 7)) << 3));
#pragma unroll
            for (int nf = 0; nf < 4; nf++) {
                int d = (nf << 4) + l15;
                short8 vb = *(const short8*)(lV + d * 64 + ((slot ^ (d & 7)) << 3));
                oacc[nf] = __builtin_amdgcn_mfma_f32_16x16x32_bf16(pa, vb, oacc[nf], 0, 0, 0);
            }
        }
    }
    long long obase = (long long)b * L_ * D_ + h * HD_;
#pragma unroll
    for (int r = 0; r < 4; r++) {
        int gr = q0 + (w << 4) + (lg << 2) + r;
        if (gr >= L_) continue;
        float inv = 1.f / l[r];
        long long ob = obase + (long long)gr * D_;
#pragma unroll
        for (int nf = 0; nf < 4; nf++)
            out[ob + (nf << 4) + l15] = f2bf(oacc[nf][r] * inv);
    }
}

// ---------------------------------------------------------------------------
// gemm launcher: 1D grid + XCD swizzle. mode 0 iff G>1 (requires G%8==0).
// ---------------------------------------------------------------------------
static inline void gemm(hipStream_t st, const unsigned short* A, const unsigned short* WTp,
                        const float* b0, const float* b1, const float* b2,
                        const float* res, const float* xg, void* C,
                        int M, int N, int K, int ldwk, int G,
                        long long sAb, long long sWb, long long sBb,
                        long long sRb, long long sCb,
                        float alpha, float alpha1, int relu, int biasmode,
                        int resmode, int outbf16)
{
    int NX = N / 128;
    int NY = (M + 127) >> 7;
    int mode = (G > 1) ? 0 : 1;
    int NYp = mode ? ((NY + 7) & ~7) : NY;
    int nblk = mode ? (NYp * NX) : (G * NY * NX);
    k_gemm_mfma<<<nblk, 256, 0, st>>>(A, WTp, b0, b1, b2, res, xg, C,
                                      M, N, K, ldwk, NX, NY, mode,
                                      sAb, sWb, sBb, sRb, sCb,
                                      alpha, alpha1, relu, biasmode, resmode, outbf16);
}

extern "C" void kernel_launch(void* const* d_in, const int* in_sizes, int n_in,
                              void* d_out, int out_size, void* d_ws, size_t ws_size,
                              hipStream_t stream)
{
    (void)in_sizes; (void)n_in; (void)out_size; (void)ws_size;
    const float* x      = (const float*)d_in[0];
    const float* g_ln_g = (const float*)d_in[2];
    const float* g_ln_b = (const float*)d_in[3];
    const float* Wq = (const float*)d_in[4];
    const float* Wk = (const float*)d_in[5];
    const float* Wv = (const float*)d_in[6];
    const float* Wo = (const float*)d_in[7];
    const float* bq = (const float*)d_in[8];
    const float* bk = (const float*)d_in[9];
    const float* bv = (const float*)d_in[10];
    const float* bo = (const float*)d_in[11];
    const float* f_ln_g = (const float*)d_in[12];
    const float* f_ln_b = (const float*)d_in[13];
    const float* W1 = (const float*)d_in[14];
    const float* b1 = (const float*)d_in[15];
    const float* W2 = (const float*)d_in[16];
    const float* b2 = (const float*)d_in[17];
    const float* c_ln_g = (const float*)d_in[18];
    const float* c_ln_b = (const float*)d_in[19];
    const float* cWq = (const float*)d_in[20];
    const float* cWk = (const float*)d_in[21];
    const float* cWv = (const float*)d_in[22];
    const float* cWo = (const float*)d_in[23];
    const float* cbq = (const float*)d_in[24];
    const float* cbk = (const float*)d_in[25];
    const float* cbv = (const float*)d_in[26];
    const float* cbo = (const float*)d_in[27];
    const float* cf_ln_g = (const float*)d_in[28];
    const float* cf_ln_b = (const float*)d_in[29];
    const float* cW1 = (const float*)d_in[30];
    const float* cb1 = (const float*)d_in[31];
    const float* cW2 = (const float*)d_in[32];
    const float* cb2 = (const float*)d_in[33];

    // ---- workspace layout (236 MB) ----
    char* wsb = (char*)d_ws;
    float*          bA   = (float*)wsb;                              // 64MB f32: hcl -> clips_out -> h
    unsigned short* bB   = (unsigned short*)(wsb + (64ll  << 20));   // 32MB bf16 activations
    unsigned short* bQKV = (unsigned short*)(wsb + (96ll  << 20));   // 92MB: fused qkv / fmid chunks
    unsigned short* wT   = (unsigned short*)(wsb + (188ll << 20));   // 48MB: weight transposes

    const long long sA   = (long long)MC_ * D_;
    const long long sQKV = (long long)MC_ * QKVS;
    const long long sWW  = (long long)D_ * D_;
    const int MG = B_ * L_;

    // ================= clip path =================
    k_ln<<<B_ * MC_, 256, 0, stream>>>(x, bB, c_ln_g, c_ln_b, MC_, D_, 2);   // cn (fused gather)
    k_wt_stack<<<dim3(16, 16, 3 * B_), 256, 0, stream>>>(cWq, cWk, cWv, nullptr,
                                                         wT, B_, 3, sWW);
    gemm(stream, bB, wT, cbq, cbk, cbv, nullptr, nullptr, bQKV,
         MC_, QKVS, D_, D_, B_, sA, 3 * sWW, D_, 0, sQKV,
         QS, 1.0f, 0, 3, 0, 1);                                              // fused clip QKV
    k_clip_attn<<<B_ * NC_ * H_, 256, 0, stream>>>(bQKV, bB);                // ctx -> bB
    k_wt<<<dim3(16, 16, B_), 256, 0, stream>>>(cWo, wT, D_, D_, sWW, sWW);
    gemm(stream, bB, wT, cbo, nullptr, nullptr, nullptr, x, bA,
         MC_, D_, D_, D_, B_, sA, sWW, D_, 0, sA,
         1.0f, 1.0f, 0, 1, 2, 0);                                            // hcl f32 -> bA
    k_ln<<<B_ * MC_, 256, 0, stream>>>(bA, bB, cf_ln_g, cf_ln_b, MC_, D_, 0); // fn
    for (int c = 0; c < 2; c++) {   // clip FFN, 2 chunks of 1024
        k_wt<<<dim3(32, 16, B_), 256, 0, stream>>>(cW1 + c * 1024, wT, FF_, D_,
                                                   (long long)D_ * FF_, 1024ll * D_);
        gemm(stream, bB, wT, cb1 + c * 1024, nullptr, nullptr, nullptr, nullptr, bQKV,
             MC_, 1024, D_, D_, B_, sA, 1024ll * D_, FF_, 0, (long long)MC_ * 1024,
             1.0f, 1.0f, 1, 1, 0, 1);                                        // fmid chunk (relu)
        k_wt<<<dim3(16, 32, B_), 256, 0, stream>>>(cW2 + (long long)c * 1024 * D_, wT,
                                                   D_, 1024, (long long)FF_ * D_,
                                                   (long long)D_ * 1024);
        gemm(stream, bQKV, wT, cb2, nullptr, nullptr, bA, nullptr, bA,
             MC_, D_, 1024, 1024, B_, (long long)MC_ * 1024, (long long)D_ * 1024,
             D_, sA, sA, 1.0f, 1.0f, 0, (c == 0) ? 1 : 0, 1, 0);             // clips_out in-place bA
    }

    // ================= global path =================
    unsigned short* gQKVO = wT;                    // [2048][512]
    unsigned short* gW1   = wT + 4 * 262144;       // [2048][512]
    unsigned short* gW2   = wT + 8 * 262144;       // [512][2048]
    k_wt_stack<<<dim3(16, 16, 4), 256, 0, stream>>>(Wq, Wk, Wv, Wo, gQKVO, 1, 4, 0);
    k_wt<<<dim3(64, 16, 1), 256, 0, stream>>>(W1, gW1, FF_, D_, 0, 0);
    k_wt<<<dim3(16, 64, 1), 256, 0, stream>>>(W2, gW2, D_, FF_, 0, 0);

    k_ln<<<MG, 256, 0, stream>>>(bA, bB, g_ln_g, g_ln_b, L_, 0, 1);          // xn (x_rec gather)
    gemm(stream, bB, gQKVO, bq, bk, bv, nullptr, nullptr, bQKV,
         MG, QKVS, D_, D_, 1, 0, 0, 0, 0, 0,
         QS, 1.0f, 0, 3, 0, 1);                                              // fused global QKV
    k_flash_mfma<<<B_ * H_ * NQT_, 256, 0, stream>>>(bQKV, bB);              // ctx2 -> bB
    gemm(stream, bB, gQKVO + 3 * 262144, bo, nullptr, nullptr, x, nullptr, bA,
         MG, D_, D_, D_, 1, 0, 0, 0, 0, 0,
         1.0f, 1.0f, 0, 1, 1, 0);                                            // h f32 -> bA (res=x)
    k_ln<<<MG, 256, 0, stream>>>(bA, bB, f_ln_g, f_ln_b, MG, 0, 0);          // hn
    for (int c = 0; c < 2; c++) {    // global FFN, 2 chunks of 1024
        gemm(stream, bB, gW1 + (long long)c * 1024 * 512, b1 + c * 1024,
             nullptr, nullptr, nullptr, nullptr, bQKV,
             MG, 1024, D_, D_, 1, 0, 0, 0, 0, 0,
             1.0f, 1.0f, 1, 1, 0, 1);                                        // mid2 chunk (relu)
        gemm(stream, bQKV, gW2 + c * 1024, b2, nullptr, nullptr,
             (c == 0) ? bA : (float*)d_out, nullptr, d_out,
             MG, D_, 1024, FF_, 1, 0, 0, 0, 0, 0,
             1.0f, 1.0f, 0, (c == 0) ? 1 : 0, 1, 0);                         // out (in-place c=1)
    }
}

// Round 10
// 1890.351 us; speedup vs baseline: 5.0074x; 1.0583x over previous
//
#include <hip/hip_runtime.h>

#define B_   32
#define L_   796
#define D_   512
#define H_   8
#define HD_  64
#define FF_  2048
#define CS_  16
#define STR_ 13
#define NC_  61
#define NQT_ 13
#define MC_  976            // NC_*CS_ rows per batch (clip path)
#define QKVS 1536           // fused QKV row stride
#define QS   (0.125f * 1.44269504f)   // 1/sqrt(64) * log2(e)  -> exp2 softmax

typedef __attribute__((ext_vector_type(8))) short short8;
typedef __attribute__((ext_vector_type(4))) float f32x4;

__device__ __forceinline__ unsigned short f2bf(float x) {
    unsigned u = __float_as_uint(x);
    unsigned r = u + 0x7FFFu + ((u >> 16) & 1u);   // RNE
    return (unsigned short)(r >> 16);
}
__device__ __forceinline__ float bf2f(unsigned short h) {
    return __uint_as_float(((unsigned)h) << 16);
}
__device__ __forceinline__ float ex2(float x) {      // native v_exp_f32 (2^x)
    return __builtin_amdgcn_exp2f(x);
}
__device__ __forceinline__ void gload16(const unsigned short* g, unsigned short* l) {
    __builtin_amdgcn_global_load_lds(
        (const __attribute__((address_space(1))) void*)g,
        (__attribute__((address_space(3))) void*)l, 16, 0, 0);
}
// Release-side drain: all of this wave's outstanding global_load_lds have
// landed in LDS before we cross the following barrier (T3 recipe: vmcnt(0)
// is EXPLICIT — the implicit __syncthreads drain is not sufficient in the
// double-buffered structure; round-9 race).
__device__ __forceinline__ void vm_drain() {
    asm volatile("s_waitcnt vmcnt(0)" ::: "memory");
}

// ---------------------------------------------------------------------------
// LayerNorm D=512, f32 in -> bf16 out.
// gather=0: direct rows; gather=1: x_rec remap; gather=2: clip build from x.
// ---------------------------------------------------------------------------
__global__ __launch_bounds__(256) void k_ln(const float* __restrict__ in,
                                            unsigned short* __restrict__ out,
                                            const float* __restrict__ gamma,
                                            const float* __restrict__ beta,
                                            int rows_per_batch, int gstride, int gather)
{
    __shared__ float red[8];
    long long row = blockIdx.x;
    int tid = threadIdx.x;
    int b;
    float v0, v1;
    if (gather == 2) {
        b = (int)(row / MC_);
        int rr = (int)(row % MC_);
        int n = rr >> 4, c = rr & 15;
        long long xb = (long long)b * L_ * D_;
        int d0 = tid, st0, sd0;
        if (d0 < 128) { st0 = n * STR_ + c; sd0 = d0; }
        else { int j = d0 - 128; st0 = n * STR_ + (j & 15); sd0 = 128 + ((j >> 4) << 4) + c; }
        v0 = in[xb + (long long)st0 * D_ + sd0];
        int j1 = tid + 128;                 // (tid+256)-128
        int st1 = n * STR_ + (j1 & 15), sd1 = 128 + ((j1 >> 4) << 4) + c;
        v1 = in[xb + (long long)st1 * D_ + sd1];
    } else {
        long long srow = row;
        if (gather == 1) {
            int p = (int)(row % L_);
            b = (int)(row / L_);
            int ci = p / STR_; if (ci > NC_ - 1) ci = NC_ - 1;
            srow = ((long long)b * NC_ + ci) * CS_ + (p - ci * STR_);
        } else {
            b = (int)(row / rows_per_batch);
        }
        const float* xr = in + srow * D_;
        v0 = xr[tid]; v1 = xr[tid + 256];
    }
    float s = v0 + v1;
#pragma unroll
    for (int off = 1; off < 64; off <<= 1) s += __shfl_xor(s, off);
    if ((tid & 63) == 0) red[tid >> 6] = s;
    __syncthreads();
    float mean = (red[0] + red[1] + red[2] + red[3]) * (1.0f / 512.0f);
    float d0 = v0 - mean, d1 = v1 - mean;
    float vv = d0 * d0 + d1 * d1;
#pragma unroll
    for (int off = 1; off < 64; off <<= 1) vv += __shfl_xor(vv, off);
    if ((tid & 63) == 0) red[4 + (tid >> 6)] = vv;
    __syncthreads();
    float var = (red[4] + red[5] + red[6] + red[7]) * (1.0f / 512.0f);
    float rstd = rsqrtf(var + 1e-6f);
    const float* g  = gamma + (long long)b * gstride;
    const float* bt = beta  + (long long)b * gstride;
    unsigned short* o = out + row * D_;
    o[tid]       = f2bf(d0 * rstd * g[tid]       + bt[tid]);
    o[tid + 256] = f2bf(d1 * rstd * g[tid + 256] + bt[tid + 256]);
}

// ---------------------------------------------------------------------------
// Weight transpose+convert: W f32 [K x N] (row stride rowStride) -> T bf16
// [N][K] (row stride tStride). grid (N/32, K/32, G).
// ---------------------------------------------------------------------------
__global__ __launch_bounds__(256) void k_wt(const float* __restrict__ W,
                                            unsigned short* __restrict__ T,
                                            int rowStride, int tStride,
                                            long long sWb, long long sTb)
{
    __shared__ float t[32][33];
    int z = blockIdx.z;
    const float* Wz = W + (long long)z * sWb;
    unsigned short* Tz = T + (long long)z * sTb;
    int n0 = blockIdx.x << 5, k0 = blockIdx.y << 5;
    int tx = threadIdx.x & 31, ty = threadIdx.x >> 5;
#pragma unroll
    for (int i = 0; i < 4; i++) {
        int k = ty + (i << 3);
        t[k][tx] = Wz[(long long)(k0 + k) * rowStride + n0 + tx];
    }
    __syncthreads();
#pragma unroll
    for (int i = 0; i < 4; i++) {
        int n = ty + (i << 3);
        Tz[(long long)(n0 + n) * tStride + k0 + tx] = f2bf(t[tx][n]);
    }
}

// Stacked transpose of up to 4 square 512x512 tensors x nb batches.
// z = tensor*nb + batch. dst: [batch][tensor*512 + n][512].
__global__ __launch_bounds__(256) void k_wt_stack(const float* __restrict__ Wa,
                                                  const float* __restrict__ Wb,
                                                  const float* __restrict__ Wc,
                                                  const float* __restrict__ Wd,
                                                  unsigned short* __restrict__ T,
                                                  int nb, int ntens, long long sWb)
{
    __shared__ float t[32][33];
    int z = blockIdx.z;
    int tt = z / nb, b = z % nb;
    const float* Wz = (tt == 0 ? Wa : tt == 1 ? Wb : tt == 2 ? Wc : Wd)
                      + (long long)b * sWb;
    unsigned short* Tz = T + ((long long)b * ntens + tt) * (512 * 512);
    int n0 = blockIdx.x << 5, k0 = blockIdx.y << 5;
    int tx = threadIdx.x & 31, ty = threadIdx.x >> 5;
#pragma unroll
    for (int i = 0; i < 4; i++) {
        int k = ty + (i << 3);
        t[k][tx] = Wz[(long long)(k0 + k) * 512 + n0 + tx];
    }
    __syncthreads();
#pragma unroll
    for (int i = 0; i < 4; i++) {
        int n = ty + (i << 3);
        Tz[(long long)(n0 + n) * 512 + k0 + tx] = f2bf(t[tx][n]);
    }
}

// ---------------------------------------------------------------------------
// bf16 MFMA GEMM, double-buffered global_load_lds pipeline (T3 recipe):
//   STAGE(buf^1, tile kt+1); compute buf; vmcnt(0) [EXPLICIT]; barrier.
// LDS 64KB (2x32KB). XCD swizzle (T1): mode 0 batched (xcd=z&7),
// mode 1 row-panel (xcd=y&7). biasmode: 0 none, 1 single, 3 triple-512.
// resmode: 0 none, 1 f32 res (may alias Cout elementwise), 2 clip-gather.
// ---------------------------------------------------------------------------
__global__ __launch_bounds__(256) void k_gemm_mfma(
    const unsigned short* __restrict__ A, const unsigned short* __restrict__ WT,
    const float* __restrict__ b0p, const float* __restrict__ b1p,
    const float* __restrict__ b2p,
    const float* res, const float* __restrict__ xg, void* Cout,
    int M, int N, int K, int ldwk, int NX, int NYd, int mode,
    long long sAb, long long sWb, long long sBb, long long sRb, long long sCb,
    float alpha, float alpha1, int relu, int biasmode, int resmode, int outbf16)
{
    __shared__ unsigned short lds[32768];      // 64 KB: 2 x (A 16KB + W 16KB)
    int tid = threadIdx.x;

    // ---- XCD-aware decode ----
    int bid = blockIdx.x;
    int xcd = bid & 7, inner = bid >> 3;
    int x = inner % NX, t = inner / NX;
    int y, z;
    if (mode == 0) { y = t % NYd; z = (t / NYd) * 8 + xcd; }
    else           { y = t * 8 + xcd; z = 0; }
    int row0 = y << 7, col0 = x << 7;
    if (row0 >= M) return;                 // padded row-tile (mode 1)

    const unsigned short* Ab = A + z * sAb;
    const unsigned short* Wb = WT + z * sWb;

    int w = tid >> 6, lane = tid & 63;
    int wr = (w >> 1) << 6, wc = (w & 1) << 6;
    int l15 = lane & 15, lg = lane >> 4;
    int lrow = lane >> 3, lslot = lane & 7;

    f32x4 acc[4][4];
#pragma unroll
    for (int i = 0; i < 4; i++)
#pragma unroll
        for (int j = 0; j < 4; j++) acc[i][j] = (f32x4)0.f;

    const int nt = K >> 6;

    // ---- prologue: stage tile 0 into buffer 0 ----
    {
        unsigned short* lA = lds;
        unsigned short* lW = lds + 8192;
#pragma unroll
        for (int i = 0; i < 4; i++) {
            int cb = (w << 5) + (i << 3);
            int rr = cb + lrow;
            gload16(Ab + (long long)(row0 + rr) * K + ((lslot ^ (rr & 7)) << 3),
                    lA + (cb << 6));
            gload16(Wb + (long long)(col0 + rr) * ldwk + ((lslot ^ (rr & 7)) << 3),
                    lW + (cb << 6));
        }
    }
    vm_drain();
    __syncthreads();

    int cur = 0;
    for (int kt = 0; kt < nt; ++kt) {
        // issue next tile's loads into the idle buffer (async, overlaps MFMA)
        if (kt + 1 < nt) {
            int k0 = (kt + 1) << 6;
            unsigned short* lA = lds + ((cur ^ 1) << 14);
            unsigned short* lW = lA + 8192;
#pragma unroll
            for (int i = 0; i < 4; i++) {
                int cb = (w << 5) + (i << 3);
                int rr = cb + lrow;
                gload16(Ab + (long long)(row0 + rr) * K + k0 + ((lslot ^ (rr & 7)) << 3),
                        lA + (cb << 6));
                gload16(Wb + (long long)(col0 + rr) * ldwk + k0 + ((lslot ^ (rr & 7)) << 3),
                        lW + (cb << 6));
            }
        }
        // compute current buffer
        {
            unsigned short* lA = lds + (cur << 14);
            unsigned short* lW = lA + 8192;
#pragma unroll
            for (int ks = 0; ks < 2; ks++) {
                short8 af[4], bfr[4];
#pragma unroll
                for (int mf = 0; mf < 4; mf++) {
                    int r = wr + (mf << 4) + l15;
                    int slot = ((ks << 2) + lg) ^ (r & 7);
                    af[mf] = *(const short8*)(lA + (r << 6) + (slot << 3));
                }
#pragma unroll
                for (int nf = 0; nf < 4; nf++) {
                    int r = wc + (nf << 4) + l15;
                    int slot = ((ks << 2) + lg) ^ (r & 7);
                    bfr[nf] = *(const short8*)(lW + (r << 6) + (slot << 3));
                }
#pragma unroll
                for (int mf = 0; mf < 4; mf++)
#pragma unroll
                    for (int nf = 0; nf < 4; nf++)
                        acc[mf][nf] = __builtin_amdgcn_mfma_f32_16x16x32_bf16(
                            af[mf], bfr[nf], acc[mf][nf], 0, 0, 0);
            }
        }
        if (kt + 1 < nt) {
            vm_drain();            // EXPLICIT release-side drain (T3 recipe)
            __syncthreads();       // next tile resident for all waves
        }
        cur ^= 1;
    }

#pragma unroll
    for (int mf = 0; mf < 4; mf++) {
#pragma unroll
        for (int reg = 0; reg < 4; reg++) {
            int gr = row0 + wr + (mf << 4) + (lg << 2) + reg;
            if (gr >= M) continue;
#pragma unroll
            for (int nf = 0; nf < 4; nf++) {
                int gc = col0 + wc + (nf << 4) + l15;
                float v = acc[mf][nf][reg];
                if (biasmode == 1) v += b0p[z * sBb + gc];
                else if (biasmode == 3) {
                    const float* bp = gc < 512 ? b0p : (gc < 1024 ? b1p : b2p);
                    v += bp[z * sBb + (gc & 511)];
                }
                v *= (gc < 512) ? alpha : alpha1;
                if (relu) v = fmaxf(v, 0.f);
                if (resmode == 1) {
                    v += res[z * sRb + (long long)gr * N + gc];
                } else if (resmode == 2) {
                    int n = gr >> 4, c = gr & 15;
                    int st, sd;
                    if (gc < 128) { st = n * STR_ + c; sd = gc; }
                    else {
                        int jj = gc - 128;
                        st = n * STR_ + (jj & 15);
                        sd = 128 + ((jj >> 4) << 4) + c;
                    }
                    v += xg[((long long)z * L_ + st) * D_ + sd];
                }
                long long co = z * sCb + (long long)gr * N + gc;
                if (outbf16) ((unsigned short*)Cout)[co] = f2bf(v);
                else         ((float*)Cout)[co] = v;
            }
        }
    }
}

// ---------------------------------------------------------------------------
// Clip attention on fused QKV (stride QKVS, offsets 0/512/1024), exp2 softmax.
// ---------------------------------------------------------------------------
__global__ __launch_bounds__(256) void k_clip_attn(const unsigned short* __restrict__ qkv,
                                                   unsigned short* __restrict__ ctx)
{
    __shared__ float qs[CS_][65], ks[CS_][65], vs[CS_][65], ps[CS_][17];
    int id = blockIdx.x;
    int h = id & (H_ - 1);
    int n = (id / H_) % NC_;
    int b = id / (H_ * NC_);
    long long base = (((long long)b * NC_ + n) * CS_) * QKVS + h * HD_;
    int tid = threadIdx.x;
#pragma unroll
    for (int i = 0; i < 4; i++) {
        int e = tid + i * 256;
        int r = e >> 6, c = e & 63;
        long long ro = base + (long long)r * QKVS + c;
        qs[r][c] = bf2f(qkv[ro]);
        ks[r][c] = bf2f(qkv[ro + 512]);
        vs[r][c] = bf2f(qkv[ro + 1024]);
    }
    __syncthreads();
    int qr = tid >> 4, kc = tid & 15;
    float s = 0.f;
#pragma unroll
    for (int d = 0; d < HD_; d++) s += qs[qr][d] * ks[kc][d];
    float m = s;
#pragma unroll
    for (int off = 1; off < 16; off <<= 1) m = fmaxf(m, __shfl_xor(m, off));
    float e = ex2(s - m);
    float sum = e;
#pragma unroll
    for (int off = 1; off < 16; off <<= 1) sum += __shfl_xor(sum, off);
    ps[qr][kc] = e / sum;
    __syncthreads();
    int dg = (tid & 15) * 4;
    float o0 = 0, o1 = 0, o2 = 0, o3 = 0;
#pragma unroll
    for (int kk = 0; kk < CS_; kk++) {
        float pp = ps[qr][kk];
        o0 += pp * vs[kk][dg + 0];
        o1 += pp * vs[kk][dg + 1];
        o2 += pp * vs[kk][dg + 2];
        o3 += pp * vs[kk][dg + 3];
    }
    long long ob = ((((long long)b * NC_ + n) * CS_) + qr) * D_ + h * HD_ + dg;
    ctx[ob + 0] = f2bf(o0);
    ctx[ob + 1] = f2bf(o1);
    ctx[ob + 2] = f2bf(o2);
    ctx[ob + 3] = f2bf(o3);
}

// ---------------------------------------------------------------------------
// Global flash attention (MFMA, exp2 softmax) on fused QKV buffer.
// XCD swizzle: bid = (b*NQT + qt)*8 + h -> all q-tiles of (b,h) on one XCD.
// (simple issue->barrier->read pattern, proven across rounds — untouched)
// ---------------------------------------------------------------------------
__global__ __launch_bounds__(256) void k_flash_mfma(
    const unsigned short* __restrict__ qkv,
    unsigned short* __restrict__ out)
{
    __shared__ unsigned short lQ[4096], lK[4096], lV[4096], lP[4096];
    int bid = blockIdx.x;
    int h  = bid & 7;                 // = (b*8+h)&7, partition by head
    int inner = bid >> 3;
    int qt = inner % NQT_;
    int b  = inner / NQT_;
    int tid = threadIdx.x;
    int q0 = qt * 64;
    long long base = (long long)b * L_ * QKVS + h * HD_;

    int w = tid >> 6, lane = tid & 63;
    int l15 = lane & 15, lg = lane >> 4;
    int lrow = lane >> 3, lslot = lane & 7;
    int srow = lane;
    int sd0  = w << 4;

#pragma unroll
    for (int i = 0; i < 2; i++) {
        int cb = (w << 4) + (i << 3);
        int rr = cb + lrow;
        gload16(qkv + base + (long long)(q0 + rr) * QKVS + ((lslot ^ (rr & 7)) << 3),
                lQ + (cb << 6));
    }
    __syncthreads();

    int qrow = (w << 4) + l15;
    short8 qf[2];
#pragma unroll
    for (int ks = 0; ks < 2; ks++) {
        int slot = (ks << 2) + lg;
        qf[ks] = *(const short8*)(lQ + qrow * 64 + ((slot ^ (qrow & 7)) << 3));
    }
    unsigned short* lPw = lP + (w << 10);

    float m[4], l[4];
    f32x4 oacc[4];
#pragma unroll
    for (int r = 0; r < 4; r++) { m[r] = -1e30f; l[r] = 0.f; }
#pragma unroll
    for (int nf = 0; nf < 4; nf++) oacc[nf] = (f32x4)0.f;

    for (int kt = 0; kt < NQT_; kt++) {
        int k0 = kt * 64;
        __syncthreads();
#pragma unroll
        for (int i = 0; i < 2; i++) {
            int cb = (w << 4) + (i << 3);
            int rr = cb + lrow;
            gload16(qkv + base + 512 + (long long)(k0 + rr) * QKVS + ((lslot ^ (rr & 7)) << 3),
                    lK + (cb << 6));
        }
        {
            int gr = k0 + srow;
            short8 v0 = (short8)0, v1 = (short8)0;
            if (gr < L_) {
                const unsigned short* pv = qkv + base + 1024 + (long long)gr * QKVS + sd0;
                v0 = *(const short8*)pv;
                v1 = *(const short8*)(pv + 8);
            }
            int ts = srow >> 3, t7 = srow & 7;
#pragma unroll
            for (int i = 0; i < 8; i++) {
                int d = sd0 + i;
                lV[d * 64 + ((ts ^ (d & 7)) << 3) + t7] = (unsigned short)v0[i];
            }
#pragma unroll
            for (int i = 0; i < 8; i++) {
                int d = sd0 + 8 + i;
                lV[d * 64 + ((ts ^ (d & 7)) << 3) + t7] = (unsigned short)v1[i];
            }
        }
        __syncthreads();

        f32x4 acc[4];
#pragma unroll
        for (int nf = 0; nf < 4; nf++) {
            acc[nf] = (f32x4)0.f;
            int tok = (nf << 4) + l15;
            int key = tok & 7;
#pragma unroll
            for (int ks = 0; ks < 2; ks++) {
                int slot = (ks << 2) + lg;
                short8 kf = *(const short8*)(lK + tok * 64 + ((slot ^ key) << 3));
                acc[nf] = __builtin_amdgcn_mfma_f32_16x16x32_bf16(qf[ks], kf, acc[nf], 0, 0, 0);
            }
        }
        float rm[4];
#pragma unroll
        for (int r = 0; r < 4; r++) rm[r] = -1e30f;
#pragma unroll
        for (int nf = 0; nf < 4; nf++) {
            bool oob = (k0 + (nf << 4) + l15) >= L_;
#pragma unroll
            for (int r = 0; r < 4; r++) {
                if (oob) acc[nf][r] = -1e30f;
                rm[r] = fmaxf(rm[r], acc[nf][r]);
            }
        }
#pragma unroll
        for (int off = 1; off < 16; off <<= 1) {
#pragma unroll
            for (int r = 0; r < 4; r++) rm[r] = fmaxf(rm[r], __shfl_xor(rm[r], off));
        }
        float sc[4], ls[4];
#pragma unroll
        for (int r = 0; r < 4; r++) {
            float mn = fmaxf(m[r], rm[r]);
            sc[r] = ex2(m[r] - mn);
            m[r] = mn;
            ls[r] = 0.f;
        }
#pragma unroll
        for (int nf = 0; nf < 4; nf++) {
            int tok = (nf << 4) + l15;
            int slot = tok >> 3, t7 = tok & 7;
#pragma unroll
            for (int r = 0; r < 4; r++) {
                float p = ex2(acc[nf][r] - m[r]);
                ls[r] += p;
                int row = (lg << 2) + r;
                lPw[row * 64 + ((slot ^ (row & 7)) << 3) + t7] = f2bf(p);
            }
        }
#pragma unroll
        for (int off = 1; off < 16; off <<= 1) {
#pragma unroll
            for (int r = 0; r < 4; r++) ls[r] += __shfl_xor(ls[r], off);
        }
#pragma unroll
        for (int r = 0; r < 4; r++) l[r] = l[r] * sc[r] + ls[r];
#pragma unroll
        for (int nf = 0; nf < 4; nf++) {
#pragma unroll
            for (int r = 0; r < 4; r++) oacc[nf][r] *= sc[r];
        }
#pragma unroll
        for (int ks = 0; ks < 2; ks++) {
            int slot = (ks << 2) + lg;
            short8 pa = *(const short8*)(lPw + l15 * 64 + ((slot ^ (l15 & 7)) << 3));
#pragma unroll
            for (int nf = 0; nf < 4; nf++) {
                int d = (nf << 4) + l15;
                short8 vb = *(const short8*)(lV + d * 64 + ((slot ^ (d & 7)) << 3));
                oacc[nf] = __builtin_amdgcn_mfma_f32_16x16x32_bf16(pa, vb, oacc[nf], 0, 0, 0);
            }
        }
    }
    long long obase = (long long)b * L_ * D_ + h * HD_;
#pragma unroll
    for (int r = 0; r < 4; r++) {
        int gr = q0 + (w << 4) + (lg << 2) + r;
        if (gr >= L_) continue;
        float inv = 1.f / l[r];
        long long ob = obase + (long long)gr * D_;
#pragma unroll
        for (int nf = 0; nf < 4; nf++)
            out[ob + (nf << 4) + l15] = f2bf(oacc[nf][r] * inv);
    }
}

// ---------------------------------------------------------------------------
// gemm launcher: 1D grid + XCD swizzle. mode 0 iff G>1 (requires G%8==0).
// ---------------------------------------------------------------------------
static inline void gemm(hipStream_t st, const unsigned short* A, const unsigned short* WTp,
                        const float* b0, const float* b1, const float* b2,
                        const float* res, const float* xg, void* C,
                        int M, int N, int K, int ldwk, int G,
                        long long sAb, long long sWb, long long sBb,
                        long long sRb, long long sCb,
                        float alpha, float alpha1, int relu, int biasmode,
                        int resmode, int outbf16)
{
    int NX = N / 128;
    int NY = (M + 127) >> 7;
    int mode = (G > 1) ? 0 : 1;
    int NYp = mode ? ((NY + 7) & ~7) : NY;
    int nblk = mode ? (NYp * NX) : (G * NY * NX);
    k_gemm_mfma<<<nblk, 256, 0, st>>>(A, WTp, b0, b1, b2, res, xg, C,
                                      M, N, K, ldwk, NX, NY, mode,
                                      sAb, sWb, sBb, sRb, sCb,
                                      alpha, alpha1, relu, biasmode, resmode, outbf16);
}

extern "C" void kernel_launch(void* const* d_in, const int* in_sizes, int n_in,
                              void* d_out, int out_size, void* d_ws, size_t ws_size,
                              hipStream_t stream)
{
    (void)in_sizes; (void)n_in; (void)out_size; (void)ws_size;
    const float* x      = (const float*)d_in[0];
    const float* g_ln_g = (const float*)d_in[2];
    const float* g_ln_b = (const float*)d_in[3];
    const float* Wq = (const float*)d_in[4];
    const float* Wk = (const float*)d_in[5];
    const float* Wv = (const float*)d_in[6];
    const float* Wo = (const float*)d_in[7];
    const float* bq = (const float*)d_in[8];
    const float* bk = (const float*)d_in[9];
    const float* bv = (const float*)d_in[10];
    const float* bo = (const float*)d_in[11];
    const float* f_ln_g = (const float*)d_in[12];
    const float* f_ln_b = (const float*)d_in[13];
    const float* W1 = (const float*)d_in[14];
    const float* b1 = (const float*)d_in[15];
    const float* W2 = (const float*)d_in[16];
    const float* b2 = (const float*)d_in[17];
    const float* c_ln_g = (const float*)d_in[18];
    const float* c_ln_b = (const float*)d_in[19];
    const float* cWq = (const float*)d_in[20];
    const float* cWk = (const float*)d_in[21];
    const float* cWv = (const float*)d_in[22];
    const float* cWo = (const float*)d_in[23];
    const float* cbq = (const float*)d_in[24];
    const float* cbk = (const float*)d_in[25];
    const float* cbv = (const float*)d_in[26];
    const float* cbo = (const float*)d_in[27];
    const float* cf_ln_g = (const float*)d_in[28];
    const float* cf_ln_b = (const float*)d_in[29];
    const float* cW1 = (const float*)d_in[30];
    const float* cb1 = (const float*)d_in[31];
    const float* cW2 = (const float*)d_in[32];
    const float* cb2 = (const float*)d_in[33];

    // ---- workspace layout (236 MB) ----
    char* wsb = (char*)d_ws;
    float*          bA   = (float*)wsb;                              // 64MB f32: hcl -> clips_out -> h
    unsigned short* bB   = (unsigned short*)(wsb + (64ll  << 20));   // 32MB bf16 activations
    unsigned short* bQKV = (unsigned short*)(wsb + (96ll  << 20));   // 92MB: fused qkv / fmid chunks
    unsigned short* wT   = (unsigned short*)(wsb + (188ll << 20));   // 48MB: weight transposes

    const long long sA   = (long long)MC_ * D_;
    const long long sQKV = (long long)MC_ * QKVS;
    const long long sWW  = (long long)D_ * D_;
    const int MG = B_ * L_;

    // ================= clip path =================
    k_ln<<<B_ * MC_, 256, 0, stream>>>(x, bB, c_ln_g, c_ln_b, MC_, D_, 2);   // cn (fused gather)
    k_wt_stack<<<dim3(16, 16, 3 * B_), 256, 0, stream>>>(cWq, cWk, cWv, nullptr,
                                                         wT, B_, 3, sWW);
    gemm(stream, bB, wT, cbq, cbk, cbv, nullptr, nullptr, bQKV,
         MC_, QKVS, D_, D_, B_, sA, 3 * sWW, D_, 0, sQKV,
         QS, 1.0f, 0, 3, 0, 1);                                              // fused clip QKV
    k_clip_attn<<<B_ * NC_ * H_, 256, 0, stream>>>(bQKV, bB);                // ctx -> bB
    k_wt<<<dim3(16, 16, B_), 256, 0, stream>>>(cWo, wT, D_, D_, sWW, sWW);
    gemm(stream, bB, wT, cbo, nullptr, nullptr, nullptr, x, bA,
         MC_, D_, D_, D_, B_, sA, sWW, D_, 0, sA,
         1.0f, 1.0f, 0, 1, 2, 0);                                            // hcl f32 -> bA
    k_ln<<<B_ * MC_, 256, 0, stream>>>(bA, bB, cf_ln_g, cf_ln_b, MC_, D_, 0); // fn
    for (int c = 0; c < 2; c++) {   // clip FFN, 2 chunks of 1024
        k_wt<<<dim3(32, 16, B_), 256, 0, stream>>>(cW1 + c * 1024, wT, FF_, D_,
                                                   (long long)D_ * FF_, 1024ll * D_);
        gemm(stream, bB, wT, cb1 + c * 1024, nullptr, nullptr, nullptr, nullptr, bQKV,
             MC_, 1024, D_, D_, B_, sA, 1024ll * D_, FF_, 0, (long long)MC_ * 1024,
             1.0f, 1.0f, 1, 1, 0, 1);                                        // fmid chunk (relu)
        k_wt<<<dim3(16, 32, B_), 256, 0, stream>>>(cW2 + (long long)c * 1024 * D_, wT,
                                                   D_, 1024, (long long)FF_ * D_,
                                                   (long long)D_ * 1024);
        gemm(stream, bQKV, wT, cb2, nullptr, nullptr, bA, nullptr, bA,
             MC_, D_, 1024, 1024, B_, (long long)MC_ * 1024, (long long)D_ * 1024,
             D_, sA, sA, 1.0f, 1.0f, 0, (c == 0) ? 1 : 0, 1, 0);             // clips_out in-place bA
    }

    // ================= global path =================
    unsigned short* gQKVO = wT;                    // [2048][512]
    unsigned short* gW1   = wT + 4 * 262144;       // [2048][512]
    unsigned short* gW2   = wT + 8 * 262144;       // [512][2048]
    k_wt_stack<<<dim3(16, 16, 4), 256, 0, stream>>>(Wq, Wk, Wv, Wo, gQKVO, 1, 4, 0);
    k_wt<<<dim3(64, 16, 1), 256, 0, stream>>>(W1, gW1, FF_, D_, 0, 0);
    k_wt<<<dim3(16, 64, 1), 256, 0, stream>>>(W2, gW2, D_, FF_, 0, 0);

    k_ln<<<MG, 256, 0, stream>>>(bA, bB, g_ln_g, g_ln_b, L_, 0, 1);          // xn (x_rec gather)
    gemm(stream, bB, gQKVO, bq, bk, bv, nullptr, nullptr, bQKV,
         MG, QKVS, D_, D_, 1, 0, 0, 0, 0, 0,
         QS, 1.0f, 0, 3, 0, 1);                                              // fused global QKV
    k_flash_mfma<<<B_ * H_ * NQT_, 256, 0, stream>>>(bQKV, bB);              // ctx2 -> bB
    gemm(stream, bB, gQKVO + 3 * 262144, bo, nullptr, nullptr, x, nullptr, bA,
         MG, D_, D_, D_, 1, 0, 0, 0, 0, 0,
         1.0f, 1.0f, 0, 1, 1, 0);                                            // h f32 -> bA (res=x)
    k_ln<<<MG, 256, 0, stream>>>(bA, bB, f_ln_g, f_ln_b, MG, 0, 0);          // hn
    for (int c = 0; c < 2; c++) {    // global FFN, 2 chunks of 1024
        gemm(stream, bB, gW1 + (long long)c * 1024 * 512, b1 + c * 1024,
             nullptr, nullptr, nullptr, nullptr, bQKV,
             MG, 1024, D_, D_, 1, 0, 0, 0, 0, 0,
             1.0f, 1.0f, 1, 1, 0, 1);                                        // mid2 chunk (relu)
        gemm(stream, bQKV, gW2 + c * 1024, b2, nullptr, nullptr,
             (c == 0) ? bA : (float*)d_out, nullptr, d_out,
             MG, D_, 1024, FF_, 1, 0, 0, 0, 0, 0,
             1.0f, 1.0f, 0, (c == 0) ? 1 : 0, 1, 0);                         // out (in-place c=1)
    }
}